// Round 2
// baseline (2859.033 us; speedup 1.0000x reference)
//
#include <hip/hip_runtime.h>

// Problem constants: B=4, N=128, T=512, K=30 bands. All I/O fp32.
typedef const float* fp;

// ---------------- Stage 0: adjacency mask from band embeddings ----------------
__global__ __launch_bounds__(64) void k_adj(fp be, float* mask) {
  __shared__ float e[30][65];
  __shared__ float sim[30][33];
  __shared__ float A[30][33];
  int tid = threadIdx.x;
  for (int idx = tid; idx < 30 * 64; idx += 64) e[idx / 64][idx % 64] = be[idx];
  __syncthreads();
  if (tid < 30) {
    float s = 0.f;
    for (int d = 0; d < 64; d++) s += e[tid][d] * e[tid][d];
    float sc = 1.0f / (sqrtf(s) + 1e-8f);
    for (int d = 0; d < 64; d++) e[tid][d] *= sc;
  }
  __syncthreads();
  if (tid < 30) {
    for (int j = 0; j < 30; j++) {
      float s = 0.f;
      for (int d = 0; d < 64; d++) s += e[tid][d] * e[j][d];
      sim[tid][j] = s;
    }
    for (int j = 0; j < 30; j++) A[tid][j] = 0.f;
  }
  __syncthreads();
  if (tid < 30) {
    unsigned used = 0;
    for (int t = 0; t < 5; t++) {
      float best = -1e30f; int bi = 0;
      for (int j = 0; j < 30; j++)
        if (!((used >> j) & 1u) && sim[tid][j] > best) { best = sim[tid][j]; bi = j; }
      A[tid][bi] = best; used |= 1u << bi;
    }
  }
  __syncthreads();
  for (int idx = tid; idx < 900; idx += 64) {
    int i = idx / 30, j = idx % 30;
    float s = A[i][j] + A[j][i];
    mask[idx] = (s != 0.0f) ? 1.0f : 0.0f;
  }
}

// ---------------- Stage 1a: per-band QKV projections ----------------
// x[b,n,t,k] -> q,kk [pair][t][128], v [pair][t][64], pair = k*4+b
__global__ __launch_bounds__(128) void k_qkv(fp x, fp Wq, fp Wk, fp Wv,
                                             float* q, float* kk, float* v) {
  int kb = blockIdx.z, b = blockIdx.y, t0 = blockIdx.x * 8;
  int tid = threadIdx.x;
  __shared__ float xs[8][129];
  for (int idx = tid; idx < 8 * 128; idx += 128) {
    int r = idx >> 7, n = idx & 127;
    xs[r][n] = x[((long)(b * 128 + n) * 512 + (t0 + r)) * 30 + kb];
  }
  __syncthreads();
  int m = tid;
  float aq[8], ak[8], av[8];
#pragma unroll
  for (int r = 0; r < 8; r++) { aq[r] = 0.f; ak[r] = 0.f; av[r] = 0.f; }
  for (int n = 0; n < 128; n++) {
    float wq = Wq[(kb * 128 + n) * 128 + m];
    float wk = Wk[(kb * 128 + n) * 128 + m];
    float wv = (m < 64) ? Wv[(kb * 128 + n) * 64 + m] : 0.f;
#pragma unroll
    for (int r = 0; r < 8; r++) {
      float xv = xs[r][n];
      aq[r] += xv * wq; ak[r] += xv * wk; av[r] += xv * wv;
    }
  }
  long base = (long)(kb * 4 + b) * 512 + t0;
#pragma unroll
  for (int r = 0; r < 8; r++) {
    q[(base + r) * 128 + m] = aq[r];
    kk[(base + r) * 128 + m] = ak[r];
    if (m < 64) v[(base + r) * 64 + m] = av[r];
  }
}

// ---------------- Stage 1b: per-row softmax stats (max, Z, sum e^2, min) ------
__global__ __launch_bounds__(256) void k_stats(const float* q, const float* kk,
                                               float* rowstats) {
  int kb = blockIdx.z, b = blockIdx.y, t0 = blockIdx.x * 16;
  int pair = kb * 4 + b;
  int tid = threadIdx.x;
  const float* qb = q + (long)pair * 512 * 128;
  const float* kbse = kk + (long)pair * 512 * 128;
  __shared__ float qs[16][132];
  __shared__ float red[16][64][8];
  for (int idx = tid; idx < 16 * 128; idx += 256) {
    int r = idx >> 7, c = idx & 127;
    qs[r][c] = qb[(long)(t0 + r) * 128 + c];
  }
  __syncthreads();
  int rg = tid >> 6, sg = tid & 63;
  float a1[4][8], a2[4][8];
#pragma unroll
  for (int r = 0; r < 4; r++)
#pragma unroll
    for (int j = 0; j < 8; j++) { a1[r][j] = 0.f; a2[r][j] = 0.f; }
  for (int d0 = 0; d0 < 64; d0 += 4) {
    float4 q1v[4], q2v[4];
#pragma unroll
    for (int r = 0; r < 4; r++) {
      q1v[r] = *(const float4*)&qs[rg * 4 + r][d0];
      q2v[r] = *(const float4*)&qs[rg * 4 + r][64 + d0];
    }
#pragma unroll
    for (int j = 0; j < 8; j++) {
      const float* krow = kbse + (long)(sg * 8 + j) * 128;
      float4 k1 = *(const float4*)(krow + d0);
      float4 k2 = *(const float4*)(krow + 64 + d0);
#pragma unroll
      for (int r = 0; r < 4; r++) {
        a1[r][j] += q1v[r].x * k1.x + q1v[r].y * k1.y + q1v[r].z * k1.z + q1v[r].w * k1.w;
        a2[r][j] += q2v[r].x * k2.x + q2v[r].y * k2.y + q2v[r].z * k2.z + q2v[r].w * k2.w;
      }
    }
  }
#pragma unroll
  for (int r = 0; r < 4; r++) {
    int row = rg * 4 + r;
    float m1 = -1e30f, mn1 = 1e30f, m2 = -1e30f, mn2 = 1e30f;
#pragma unroll
    for (int j = 0; j < 8; j++) {
      float d1 = a1[r][j] * 0.25f, d2 = a2[r][j] * 0.25f;
      m1 = fmaxf(m1, d1); mn1 = fminf(mn1, d1);
      m2 = fmaxf(m2, d2); mn2 = fminf(mn2, d2);
    }
    float z1 = 0.f, s21 = 0.f, z2 = 0.f, s22 = 0.f;
#pragma unroll
    for (int j = 0; j < 8; j++) {
      float e1 = expf(a1[r][j] * 0.25f - m1); z1 += e1; s21 += e1 * e1;
      float e2 = expf(a2[r][j] * 0.25f - m2); z2 += e2; s22 += e2 * e2;
    }
    red[row][sg][0] = m1; red[row][sg][1] = z1; red[row][sg][2] = s21; red[row][sg][3] = mn1;
    red[row][sg][4] = m2; red[row][sg][5] = z2; red[row][sg][6] = s22; red[row][sg][7] = mn2;
  }
  __syncthreads();
  if (tid < 16) {
    float M1 = -1e30f, M2 = -1e30f, mn1 = 1e30f, mn2 = 1e30f;
    for (int e = 0; e < 64; e++) {
      M1 = fmaxf(M1, red[tid][e][0]); mn1 = fminf(mn1, red[tid][e][3]);
      M2 = fmaxf(M2, red[tid][e][4]); mn2 = fminf(mn2, red[tid][e][7]);
    }
    float Z1 = 0.f, S21 = 0.f, Z2 = 0.f, S22 = 0.f;
    for (int e = 0; e < 64; e++) {
      float f1 = expf(red[tid][e][0] - M1); Z1 += red[tid][e][1] * f1; S21 += red[tid][e][2] * f1 * f1;
      float f2 = expf(red[tid][e][4] - M2); Z2 += red[tid][e][5] * f2; S22 += red[tid][e][6] * f2 * f2;
    }
    float* o = rowstats + ((long)pair * 512 + t0 + tid) * 8;
    o[0] = M1; o[1] = Z1; o[2] = S21; o[3] = mn1;
    o[4] = M2; o[5] = Z2; o[6] = S22; o[7] = mn2;
  }
}

// ---------------- Stage 1c: matrix stats -> lambda MLP ----------------
__global__ __launch_bounds__(64) void k_lam(const float* rowstats, fp lw1, fp lb1,
                                            fp lw2, fp lb2, float* lam) {
  int pair = blockIdx.x; int kb = pair >> 2;
  int tid = threadIdx.x;
  const float* rs = rowstats + (long)pair * 512 * 8;
  float mx1 = -1e30f, mn1 = 1e30f, ss1 = 0.f, mx2 = -1e30f, mn2 = 1e30f, ss2 = 0.f;
  for (int j = 0; j < 8; j++) {
    const float* rr = rs + (long)(j * 64 + tid) * 8;
    float M1 = rr[0], Z1 = rr[1], S21 = rr[2], m1 = rr[3];
    float M2 = rr[4], Z2 = rr[5], S22 = rr[6], m2 = rr[7];
    mx1 = fmaxf(mx1, 1.0f / Z1); mn1 = fminf(mn1, expf(m1 - M1) / Z1); ss1 += S21 / (Z1 * Z1);
    mx2 = fmaxf(mx2, 1.0f / Z2); mn2 = fminf(mn2, expf(m2 - M2) / Z2); ss2 += S22 / (Z2 * Z2);
  }
  __shared__ float red[64][8];
  red[tid][0] = mx1; red[tid][1] = mn1; red[tid][2] = ss1;
  red[tid][3] = mx2; red[tid][4] = mn2; red[tid][5] = ss2;
  __syncthreads();
  if (tid == 0) {
    for (int e = 1; e < 64; e++) {
      mx1 = fmaxf(mx1, red[e][0]); mn1 = fminf(mn1, red[e][1]); ss1 += red[e][2];
      mx2 = fmaxf(mx2, red[e][3]); mn2 = fminf(mn2, red[e][4]); ss2 += red[e][5];
    }
    const float mean = 1.0f / 512.0f;
    const float n = 262144.0f;
    float v1 = (ss1 - n * mean * mean) / (n - 1.0f); float sd1 = sqrtf(fmaxf(v1, 0.f));
    float v2 = (ss2 - n * mean * mean) / (n - 1.0f); float sd2 = sqrtf(fmaxf(v2, 0.f));
    float st[8] = { mean, sd1, mx1, mn1, mean, sd2, mx2, mn2 };
    float acc = lb2[kb];
    for (int o = 0; o < 16; o++) {
      float h = lb1[kb * 16 + o];
      for (int i = 0; i < 8; i++) h += st[i] * lw1[(kb * 8 + i) * 16 + o];
      h = fmaxf(h, 0.f);
      acc += h * lw2[kb * 16 + o];
    }
    lam[pair] = 1.0f / (1.0f + expf(-acc));
  }
}

// ---------------- Stage 1d: recompute softmax, (a1 - lam a2)@V@Wo -> h1 -------
// h1 layout [B][K][T][N]
__global__ __launch_bounds__(256) void k_attnout(const float* q, const float* kk,
                                                 const float* v, const float* rowstats,
                                                 const float* lam, fp Wo, fp bo,
                                                 float* h1) {
  int kb = blockIdx.z, b = blockIdx.y, t0 = blockIdx.x * 16;
  int pair = kb * 4 + b;
  int tid = threadIdx.x;
  const float* qb = q + (long)pair * 512 * 128;
  const float* kbse = kk + (long)pair * 512 * 128;
  const float* vb = v + (long)pair * 512 * 64;
  __shared__ float qs[16][132];
  __shared__ float adL[16][520];
  __shared__ float obs[16][68];
  __shared__ float Mz[16][4];
  float lamv = lam[pair];
  for (int idx = tid; idx < 16 * 128; idx += 256) {
    int r = idx >> 7, c = idx & 127;
    qs[r][c] = qb[(long)(t0 + r) * 128 + c];
  }
  if (tid < 16) {
    const float* rr = rowstats + ((long)pair * 512 + t0 + tid) * 8;
    Mz[tid][0] = rr[0]; Mz[tid][1] = 1.0f / rr[1];
    Mz[tid][2] = rr[4]; Mz[tid][3] = 1.0f / rr[5];
  }
  __syncthreads();
  int rg = tid >> 6, sg = tid & 63;
  {
    float a1[4][8], a2[4][8];
#pragma unroll
    for (int r = 0; r < 4; r++)
#pragma unroll
      for (int j = 0; j < 8; j++) { a1[r][j] = 0.f; a2[r][j] = 0.f; }
    for (int d0 = 0; d0 < 64; d0 += 4) {
      float4 q1v[4], q2v[4];
#pragma unroll
      for (int r = 0; r < 4; r++) {
        q1v[r] = *(const float4*)&qs[rg * 4 + r][d0];
        q2v[r] = *(const float4*)&qs[rg * 4 + r][64 + d0];
      }
#pragma unroll
      for (int j = 0; j < 8; j++) {
        const float* krow = kbse + (long)(sg * 8 + j) * 128;
        float4 k1 = *(const float4*)(krow + d0);
        float4 k2 = *(const float4*)(krow + 64 + d0);
#pragma unroll
        for (int r = 0; r < 4; r++) {
          a1[r][j] += q1v[r].x * k1.x + q1v[r].y * k1.y + q1v[r].z * k1.z + q1v[r].w * k1.w;
          a2[r][j] += q2v[r].x * k2.x + q2v[r].y * k2.y + q2v[r].z * k2.z + q2v[r].w * k2.w;
        }
      }
    }
#pragma unroll
    for (int r = 0; r < 4; r++) {
      int row = rg * 4 + r;
      float M1 = Mz[row][0], i1 = Mz[row][1], M2 = Mz[row][2], i2 = Mz[row][3];
#pragma unroll
      for (int j = 0; j < 8; j++) {
        float p1 = expf(a1[r][j] * 0.25f - M1) * i1;
        float p2 = expf(a2[r][j] * 0.25f - M2) * i2;
        adL[row][sg * 8 + j] = p1 - lamv * p2;
      }
    }
  }
  __syncthreads();
  // Phase B: ob[row][d] = sum_s ad[row][s] * v[s][d]
  {
    int rh = tid >> 6, d = tid & 63;
    float ob[4] = { 0.f, 0.f, 0.f, 0.f };
    const float4* ad40 = (const float4*)&adL[rh * 4 + 0][0];
    const float4* ad41 = (const float4*)&adL[rh * 4 + 1][0];
    const float4* ad42 = (const float4*)&adL[rh * 4 + 2][0];
    const float4* ad43 = (const float4*)&adL[rh * 4 + 3][0];
    for (int s4 = 0; s4 < 128; s4++) {
      float4 x0 = ad40[s4], x1 = ad41[s4], x2 = ad42[s4], x3 = ad43[s4];
      int s = s4 * 4;
      float v0 = vb[(long)(s + 0) * 64 + d];
      float v1 = vb[(long)(s + 1) * 64 + d];
      float v2 = vb[(long)(s + 2) * 64 + d];
      float v3 = vb[(long)(s + 3) * 64 + d];
      ob[0] += x0.x * v0 + x0.y * v1 + x0.z * v2 + x0.w * v3;
      ob[1] += x1.x * v0 + x1.y * v1 + x1.z * v2 + x1.w * v3;
      ob[2] += x2.x * v0 + x2.y * v1 + x2.z * v2 + x2.w * v3;
      ob[3] += x3.x * v0 + x3.y * v1 + x3.z * v2 + x3.w * v3;
    }
#pragma unroll
    for (int rr = 0; rr < 4; rr++) obs[rh * 4 + rr][d] = ob[rr];
  }
  __syncthreads();
  // Phase C: h1 row = obs @ Wo + bo
  {
    int r = tid >> 4, ng = tid & 15;
    float acc[8];
#pragma unroll
    for (int j = 0; j < 8; j++) acc[j] = bo[kb * 128 + ng * 8 + j];
    for (int dd = 0; dd < 64; dd++) {
      float o = obs[r][dd];
#pragma unroll
      for (int j = 0; j < 8; j++) acc[j] += o * Wo[(kb * 64 + dd) * 128 + ng * 8 + j];
    }
    long hbase = ((long)(b * 30 + kb) * 512 + t0 + r) * 128 + ng * 8;
#pragma unroll
    for (int j = 0; j < 8; j++) h1[hbase + j] = acc[j];
  }
}

// ---------------- Stage 2a: combined per-band conv kernel ----------------
// ck layout [k][ni][r(32)][no], r index = signed offset + 16
__global__ __launch_bounds__(256) void k_ck(fp fw, fp cw2, fp cw4, fp cw8,
                                            fp cw16, fp cw32, float* ck) {
  int idx = blockIdx.x * 256 + threadIdx.x;
  int no = idx & 127;
  int r = (idx >> 7) & 31;
  int ni = (idx >> 12) & 127;
  int kb = idx >> 19;
  float f0 = fw[kb * 3 + 0], f1 = fw[kb * 3 + 1], f2 = fw[kb * 3 + 2];
  float mx = fmaxf(f0, fmaxf(f1, f2));
  float e0 = expf(f0 - mx), e1 = expf(f1 - mx), e2 = expf(f2 - mx);
  float zi = 1.0f / (e0 + e1 + e2);
  float sw[3] = { e0 * zi, e1 * zi, e2 * zi };
  int sbase; fp cws[3];
  if (kb < 6)       { sbase = 8; cws[0] = cw8;  cws[1] = cw16; cws[2] = cw32; }
  else if (kb < 15) { sbase = 4; cws[0] = cw4;  cws[1] = cw8;  cws[2] = cw16; }
  else              { sbase = 2; cws[0] = cw2;  cws[1] = cw4;  cws[2] = cw8;  }
  float val = 0.f;
  int rs = r - 16;
#pragma unroll
  for (int j = 0; j < 3; j++) {
    int s = sbase << j;
    int tau = rs + (s >> 1);
    if (tau >= 0 && tau < s) val += sw[j] * cws[j][((long)no * 128 + ni) * s + tau];
  }
  ck[idx] = val;
}

// ---------------- Stage 2b: per-band conv, h1 -> h2 ----------------
// h1 [B][K][T][N]; h2 [B][T][K][N] (= graph-attention xg layout)
__global__ __launch_bounds__(256) void k_conv(const float* h1, const float* ck, fp fw,
                                              fp cb2, fp cb4, fp cb8, fp cb16,
                                              fp cb32, float* h2) {
  int kb = blockIdx.z, b = blockIdx.y, t0 = blockIdx.x * 64;
  int tid = threadIdx.x;
  __shared__ float xs[128][97];
  const float* xrow = h1 + (long)(b * 30 + kb) * 512 * 128;
  for (int idx = tid; idx < 96 * 128; idx += 256) {
    int col = idx >> 7, n = idx & 127;
    int t = t0 - 16 + col;
    xs[n][col] = (t >= 0 && t < 512) ? xrow[(long)t * 128 + n] : 0.f;
  }
  int ng = tid & 15, tg = tid >> 4;  // no octet, t quad
  float f0 = fw[kb * 3 + 0], f1 = fw[kb * 3 + 1], f2 = fw[kb * 3 + 2];
  float mx = fmaxf(f0, fmaxf(f1, f2));
  float e0 = expf(f0 - mx), e1 = expf(f1 - mx), e2 = expf(f2 - mx);
  float zi = 1.0f / (e0 + e1 + e2);
  int rlo, rhi; fp c0, c1, c2;
  if (kb < 6)       { rlo = 0;  rhi = 32; c0 = cb8; c1 = cb16; c2 = cb32; }
  else if (kb < 15) { rlo = 8;  rhi = 24; c0 = cb4; c1 = cb8;  c2 = cb16; }
  else              { rlo = 12; rhi = 20; c0 = cb2; c1 = cb4;  c2 = cb8;  }
  float acc[8][4];
#pragma unroll
  for (int j = 0; j < 8; j++) {
    float cb = e0 * zi * c0[ng * 8 + j] + e1 * zi * c1[ng * 8 + j]
             + e2 * zi * c2[ng * 8 + j];
#pragma unroll
    for (int i = 0; i < 4; i++) acc[j][i] = cb;
  }
  __syncthreads();
  const float* ckb = ck + (long)kb * 524288;
  int toff = tg * 4;
  for (int ni = 0; ni < 128; ni++) {
    const float* xr0 = &xs[ni][toff];
    for (int r = rlo; r < rhi; r++) {
      float4 w0 = *(const float4*)&ckb[(ni * 32 + r) * 128 + ng * 8];
      float4 w1 = *(const float4*)&ckb[(ni * 32 + r) * 128 + ng * 8 + 4];
      float xv0 = xr0[r + 0], xv1 = xr0[r + 1], xv2 = xr0[r + 2], xv3 = xr0[r + 3];
      float wj[8] = { w0.x, w0.y, w0.z, w0.w, w1.x, w1.y, w1.z, w1.w };
#pragma unroll
      for (int j = 0; j < 8; j++) {
        acc[j][0] += wj[j] * xv0; acc[j][1] += wj[j] * xv1;
        acc[j][2] += wj[j] * xv2; acc[j][3] += wj[j] * xv3;
      }
    }
  }
#pragma unroll
  for (int i = 0; i < 4; i++) {
    long ob = ((long)(b * 512 + t0 + toff + i) * 30 + kb) * 128 + ng * 8;
    float4 s0 = { acc[0][i], acc[1][i], acc[2][i], acc[3][i] };
    float4 s1 = { acc[4][i], acc[5][i], acc[6][i], acc[7][i] };
    *(float4*)&h2[ob] = s0;
    *(float4*)&h2[ob + 4] = s1;
  }
}

// ---------------- Stage 3a: graph QKV ----------------
__global__ __launch_bounds__(128) void k_gqkv(const float* h2, fp gWq, fp gbq,
                                              fp gWk, fp gbk, fp gWv, fp gbv,
                                              float* qg, float* kg, float* vg) {
  long row0 = (long)blockIdx.x * 16;
  int m = threadIdx.x;
  __shared__ float xs[16][132];
  for (int idx = m; idx < 16 * 128; idx += 128) {
    int r = idx >> 7, c = idx & 127;
    xs[r][c] = h2[(row0 + r) * 128 + c];
  }
  __syncthreads();
  float aq[16], ak[16], av[16];
#pragma unroll
  for (int r = 0; r < 16; r++) { aq[r] = 0.f; ak[r] = 0.f; av[r] = 0.f; }
  for (int n = 0; n < 128; n++) {
    float wq = gWq[n * 128 + m], wk = gWk[n * 128 + m], wv = gWv[n * 128 + m];
#pragma unroll
    for (int r = 0; r < 16; r++) {
      float xv = xs[r][n];
      aq[r] += xv * wq; ak[r] += xv * wk; av[r] += xv * wv;
    }
  }
  float bq = gbq[m], bk = gbk[m], bv = gbv[m];
#pragma unroll
  for (int r = 0; r < 16; r++) {
    qg[(row0 + r) * 128 + m] = aq[r] + bq;
    kg[(row0 + r) * 128 + m] = ak[r] + bk;
    vg[(row0 + r) * 128 + m] = av[r] + bv;
  }
}

// ---------------- Stage 3b: graph attention + output GEMM ----------------
__global__ __launch_bounds__(128) void k_gattn(const float* qg, const float* kg,
                                               const float* vg, const float* maskw,
                                               fp gWo, fp gbo, float* out) {
  int m = blockIdx.x; int b = m >> 9; int t = m & 511;
  int tid = threadIdx.x;
  __shared__ float qs[30][132];
  __shared__ float ks[30][132];
  __shared__ float vs[30][132];
  __shared__ float msk[30][32];
  float (*ogs)[132] = qs;  // reuse qs after scores are consumed
  const float* qb = qg + (long)m * 30 * 128;
  const float* kb2 = kg + (long)m * 30 * 128;
  const float* vb2 = vg + (long)m * 30 * 128;
  for (int idx = tid; idx < 3840; idx += 128) {
    int j = idx >> 7, n = idx & 127;
    qs[j][n] = qb[idx]; ks[j][n] = kb2[idx]; vs[j][n] = vb2[idx];
  }
  for (int idx = tid; idx < 900; idx += 128) msk[idx / 30][idx % 30] = maskw[idx];
  __syncthreads();
  float p[30]; float iZ = 0.f; int hi = 0, ii = 0;
  if (tid < 120) {
    hi = tid / 30; ii = tid % 30;
    int hb = hi * 32;
    float4 qv[8];
#pragma unroll
    for (int dq = 0; dq < 8; dq++) qv[dq] = *(const float4*)&qs[ii][hb + dq * 4];
    float mx = -1e30f;
#pragma unroll
    for (int j = 0; j < 30; j++) {
      float s = 0.f;
      const float4* kr = (const float4*)&ks[j][hb];
#pragma unroll
      for (int dq = 0; dq < 8; dq++) {
        float4 kv = kr[dq];
        s += qv[dq].x * kv.x + qv[dq].y * kv.y + qv[dq].z * kv.z + qv[dq].w * kv.w;
      }
      s *= 0.17677669529663687f;
      p[j] = (msk[ii][j] != 0.f) ? s : -1e30f;
      mx = fmaxf(mx, p[j]);
    }
    float Z = 0.f;
#pragma unroll
    for (int j = 0; j < 30; j++) { float e = expf(p[j] - mx); p[j] = e; Z += e; }
    iZ = 1.0f / Z;
  }
  __syncthreads();   // everyone done reading qs
  if (tid < 120) {
    int hb = hi * 32;
#pragma unroll
    for (int dq = 0; dq < 8; dq++) {
      float sx = 0.f, sy = 0.f, sz = 0.f, sw2 = 0.f;
#pragma unroll
      for (int j = 0; j < 30; j++) {
        float4 vv = *(const float4*)&vs[j][hb + dq * 4];
        sx += p[j] * vv.x; sy += p[j] * vv.y; sz += p[j] * vv.z; sw2 += p[j] * vv.w;
      }
      float4 o = { sx * iZ, sy * iZ, sz * iZ, sw2 * iZ };
      *(float4*)&ogs[ii][hb + dq * 4] = o;
    }
  }
  __syncthreads();
  {
    int n = tid;
    float acc[30];
#pragma unroll
    for (int j = 0; j < 30; j++) acc[j] = 0.f;
    for (int d = 0; d < 128; d += 4) {
      float w0 = gWo[(d + 0) * 128 + n];
      float w1 = gWo[(d + 1) * 128 + n];
      float w2 = gWo[(d + 2) * 128 + n];
      float w3 = gWo[(d + 3) * 128 + n];
#pragma unroll
      for (int j = 0; j < 30; j++) {
        float4 og4 = *(const float4*)&ogs[j][d];
        acc[j] += og4.x * w0 + og4.y * w1 + og4.z * w2 + og4.w * w3;
      }
    }
    float gb = gbo[n];
    float* outp = out + ((long)(b * 128 + n) * 512 + t) * 30;
#pragma unroll
    for (int j = 0; j < 30; j++) outp[j] = acc[j] + gb;
  }
}

extern "C" void kernel_launch(void* const* d_in, const int* in_sizes, int n_in,
                              void* d_out, int out_size, void* d_ws, size_t ws_size,
                              hipStream_t stream) {
  fp x = (fp)d_in[0], Wq = (fp)d_in[1], Wk = (fp)d_in[2], Wv = (fp)d_in[3],
     Wo = (fp)d_in[4], bo = (fp)d_in[5], lw1 = (fp)d_in[6], lb1 = (fp)d_in[7],
     lw2 = (fp)d_in[8], lb2 = (fp)d_in[9],
     cw2 = (fp)d_in[10], cb2 = (fp)d_in[11], cw4 = (fp)d_in[12], cb4 = (fp)d_in[13],
     cw8 = (fp)d_in[14], cb8 = (fp)d_in[15], cw16 = (fp)d_in[16], cb16 = (fp)d_in[17],
     cw32 = (fp)d_in[18], cb32 = (fp)d_in[19], fw = (fp)d_in[20], be = (fp)d_in[21],
     gWq = (fp)d_in[22], gbq = (fp)d_in[23], gWk = (fp)d_in[24], gbk = (fp)d_in[25],
     gWv = (fp)d_in[26], gbv = (fp)d_in[27], gWo = (fp)d_in[28], gbo = (fp)d_in[29];
  (void)in_sizes; (void)n_in; (void)out_size; (void)ws_size;

  float* ws = (float*)d_ws;
  const long SZ = 7864320L;                 // B*N*T*K = 4*128*512*30
  // Layout (fp32 elements), with stage-ordered aliasing to cut footprint:
  float* q        = ws;                     // [120][512][128]
  float* kkb      = ws + SZ;                // [120][512][128]
  float* vbuf     = ws + 2 * SZ;            // [120][512][64]
  float* rowstats = vbuf + 3932160L;        // [120][512][8]
  float* lam      = rowstats + 491520L;     // [120]
  float* maskw    = lam + 128;              // [900]
  float* h1       = maskw + 1024;           // [B][K][T][N]
  float* h2       = h1 + SZ;                // [B][T][K][N]
  // ck aliases q+kk (dead after k_attnout); stage-3 qkv alias h1/q/kk.
  float* ck  = q;                           // [30][128][32][128] = 2*SZ
  float* qgb = h1;
  float* kgb = q;
  float* vgb = kkb;
  // total: 8*SZ/2 ... = 35,882,112 floats = 143.5 MB

  k_adj<<<1, 64, 0, stream>>>(be, maskw);
  k_qkv<<<dim3(64, 4, 30), 128, 0, stream>>>(x, Wq, Wk, Wv, q, kkb, vbuf);
  k_stats<<<dim3(32, 4, 30), 256, 0, stream>>>(q, kkb, rowstats);
  k_lam<<<120, 64, 0, stream>>>(rowstats, lw1, lb1, lw2, lb2, lam);
  k_attnout<<<dim3(32, 4, 30), 256, 0, stream>>>(q, kkb, vbuf, rowstats, lam, Wo, bo, h1);
  k_ck<<<61440, 256, 0, stream>>>(fw, cw2, cw4, cw8, cw16, cw32, ck);
  k_conv<<<dim3(8, 4, 30), 256, 0, stream>>>(h1, ck, fw, cb2, cb4, cb8, cb16, cb32, h2);
  k_gqkv<<<3840, 128, 0, stream>>>(h2, gWq, gbq, gWk, gbk, gWv, gbv, qgb, kgb, vgb);
  k_gattn<<<2048, 128, 0, stream>>>(qgb, kgb, vgb, maskw, gWo, gbo, (float*)d_out);
}

// Round 3
// 1510.459 us; speedup vs baseline: 1.8928x; 1.8928x over previous
//
#include <hip/hip_runtime.h>

// Problem constants: B=4, N=128, T=512, K=30 bands. All I/O fp32.
typedef const float* fp;
typedef unsigned short u16;
typedef __attribute__((ext_vector_type(8))) short bf16x8;   // 8 bf16 = 4 VGPRs
typedef __attribute__((ext_vector_type(4))) float f32x4;

__device__ __forceinline__ u16 f2b(float f) {
  union { float f; unsigned u; } a; a.f = f;
  unsigned u = a.u;
  u += 0x7fffu + ((u >> 16) & 1u);   // RNE
  return (u16)(u >> 16);
}
// split fp32 into hi (truncated bf16) + lo (RNE bf16 of exact remainder)
__device__ __forceinline__ void splitf(float x, u16& h, u16& l) {
  union { float f; unsigned u; } a; a.f = x;
  unsigned hu = a.u & 0xFFFF0000u;
  h = (u16)(hu >> 16);
  union { unsigned u; float f; } b; b.u = hu;
  l = f2b(x - b.f);
}

// ---------------- Stage 0: adjacency mask from band embeddings ----------------
__global__ __launch_bounds__(64) void k_adj(fp be, float* mask) {
  __shared__ float e[30][65];
  __shared__ float sim[30][33];
  __shared__ float A[30][33];
  int tid = threadIdx.x;
  for (int idx = tid; idx < 30 * 64; idx += 64) e[idx / 64][idx % 64] = be[idx];
  __syncthreads();
  if (tid < 30) {
    float s = 0.f;
    for (int d = 0; d < 64; d++) s += e[tid][d] * e[tid][d];
    float sc = 1.0f / (sqrtf(s) + 1e-8f);
    for (int d = 0; d < 64; d++) e[tid][d] *= sc;
  }
  __syncthreads();
  if (tid < 30) {
    for (int j = 0; j < 30; j++) {
      float s = 0.f;
      for (int d = 0; d < 64; d++) s += e[tid][d] * e[j][d];
      sim[tid][j] = s;
    }
    for (int j = 0; j < 30; j++) A[tid][j] = 0.f;
  }
  __syncthreads();
  if (tid < 30) {
    unsigned used = 0;
    for (int t = 0; t < 5; t++) {
      float best = -1e30f; int bi = 0;
      for (int j = 0; j < 30; j++)
        if (!((used >> j) & 1u) && sim[tid][j] > best) { best = sim[tid][j]; bi = j; }
      A[tid][bi] = best; used |= 1u << bi;
    }
  }
  __syncthreads();
  for (int idx = tid; idx < 900; idx += 64) {
    int i = idx / 30, j = idx % 30;
    float s = A[i][j] + A[j][i];
    mask[idx] = (s != 0.0f) ? 1.0f : 0.0f;
  }
}

// ---------------- Stage 1a: per-band QKV projections (split-bf16 out) ---------
// x[b,n,t,k] -> qh/ql,kh/kl [pair][t][128] bf16; vTh/vTl [pair][64][512] bf16
__global__ __launch_bounds__(128) void k_qkv(fp x, fp Wq, fp Wk, fp Wv,
                                             u16* qh, u16* ql, u16* kh, u16* kl,
                                             u16* vTh, u16* vTl) {
  int kb = blockIdx.z, b = blockIdx.y, t0 = blockIdx.x * 8;
  int tid = threadIdx.x;
  __shared__ float xs[8][129];
  for (int idx = tid; idx < 8 * 128; idx += 128) {
    int r = idx >> 7, n = idx & 127;
    xs[r][n] = x[((long)(b * 128 + n) * 512 + (t0 + r)) * 30 + kb];
  }
  __syncthreads();
  int m = tid;
  float aq[8], ak[8], av[8];
#pragma unroll
  for (int r = 0; r < 8; r++) { aq[r] = 0.f; ak[r] = 0.f; av[r] = 0.f; }
  for (int n = 0; n < 128; n++) {
    float wq = Wq[(kb * 128 + n) * 128 + m];
    float wk = Wk[(kb * 128 + n) * 128 + m];
    float wv = (m < 64) ? Wv[(kb * 128 + n) * 64 + m] : 0.f;
#pragma unroll
    for (int r = 0; r < 8; r++) {
      float xv = xs[r][n];
      aq[r] += xv * wq; ak[r] += xv * wk; av[r] += xv * wv;
    }
  }
  int pair = kb * 4 + b;
  long base = (long)pair * 512 + t0;
#pragma unroll
  for (int r = 0; r < 8; r++) {
    u16 hh, ll;
    splitf(aq[r], hh, ll); qh[(base + r) * 128 + m] = hh; ql[(base + r) * 128 + m] = ll;
    splitf(ak[r], hh, ll); kh[(base + r) * 128 + m] = hh; kl[(base + r) * 128 + m] = ll;
    if (m < 64) {
      splitf(av[r], hh, ll);
      long vo = ((long)pair * 64 + m) * 512 + t0 + r;
      vTh[vo] = hh; vTl[vo] = ll;
    }
  }
}

// ---------------- Stage 1b: fused flash kernel ----------------
// Per block: one (pair, 16-row strip). 256 threads = 4 waves; wave w owns score
// cols [w*128, w*128+128). Computes S1,S2 once via split-bf16 MFMA, row stats,
// then ob1 = softmax(S1)@v, ob2 = softmax(S2)@v via MFMA (p bf16, v split).
__global__ __launch_bounds__(256) void k_flash(const u16* qh, const u16* ql,
                                               const u16* kh, const u16* kl,
                                               const u16* vTh, const u16* vTl,
                                               float* rowstats, float* ob1, float* ob2) {
  int pair = blockIdx.y;
  int t0 = blockIdx.x * 16;
  int tid = threadIdx.x;
  int wave = tid >> 6, lane = tid & 63;
  int l15 = lane & 15, quad = lane >> 4;

  __shared__ float fbig[8704];          // phase-B p-buffer (u16[2][4][16][136]) then obr (f32[4][2][16][68])
  __shared__ float st[2][16][4][4];
  __shared__ float fin[2][16][2];

  const long pb = (long)pair * 512 * 128;
  const u16* qhb = qh + pb; const u16* qlb = ql + pb;
  const u16* khb = kh + pb; const u16* klb = kl + pb;

  float sc[2][8][4];
  // ---- Phase A: scores (MFMA, hh+hl+lh split products) ----
#pragma unroll
  for (int h = 0; h < 2; h++) {
    long abase = (long)(t0 + l15) * 128 + h * 64 + quad * 8;
    bf16x8 Ah0 = *(const bf16x8*)(qhb + abase);
    bf16x8 Ah1 = *(const bf16x8*)(qhb + abase + 32);
    bf16x8 Al0 = *(const bf16x8*)(qlb + abase);
    bf16x8 Al1 = *(const bf16x8*)(qlb + abase + 32);
#pragma unroll
    for (int ct = 0; ct < 8; ct++) {
      int scol = wave * 128 + ct * 16 + l15;
      long bbase = (long)scol * 128 + h * 64 + quad * 8;
      bf16x8 Bh0 = *(const bf16x8*)(khb + bbase);
      bf16x8 Bh1 = *(const bf16x8*)(khb + bbase + 32);
      bf16x8 Bl0 = *(const bf16x8*)(klb + bbase);
      bf16x8 Bl1 = *(const bf16x8*)(klb + bbase + 32);
      f32x4 d = {0.f, 0.f, 0.f, 0.f};
      d = __builtin_amdgcn_mfma_f32_16x16x32_bf16(Ah0, Bh0, d, 0, 0, 0);
      d = __builtin_amdgcn_mfma_f32_16x16x32_bf16(Ah1, Bh1, d, 0, 0, 0);
      d = __builtin_amdgcn_mfma_f32_16x16x32_bf16(Ah0, Bl0, d, 0, 0, 0);
      d = __builtin_amdgcn_mfma_f32_16x16x32_bf16(Ah1, Bl1, d, 0, 0, 0);
      d = __builtin_amdgcn_mfma_f32_16x16x32_bf16(Al0, Bh0, d, 0, 0, 0);
      d = __builtin_amdgcn_mfma_f32_16x16x32_bf16(Al1, Bh1, d, 0, 0, 0);
#pragma unroll
      for (int r = 0; r < 4; r++) sc[h][ct][r] = d[r] * 0.25f;
    }
  }
  // ---- row stats: per-wave partials via 16-lane shuffles ----
#pragma unroll
  for (int h = 0; h < 2; h++)
#pragma unroll
    for (int r = 0; r < 4; r++) {
      float m = -1e30f, mnv = 1e30f;
#pragma unroll
      for (int ct = 0; ct < 8; ct++) { m = fmaxf(m, sc[h][ct][r]); mnv = fminf(mnv, sc[h][ct][r]); }
      for (int d = 1; d < 16; d <<= 1) { m = fmaxf(m, __shfl_xor(m, d)); mnv = fminf(mnv, __shfl_xor(mnv, d)); }
      float z = 0.f, s2 = 0.f;
#pragma unroll
      for (int ct = 0; ct < 8; ct++) { float e = expf(sc[h][ct][r] - m); z += e; s2 += e * e; }
      for (int d = 1; d < 16; d <<= 1) { z += __shfl_xor(z, d); s2 += __shfl_xor(s2, d); }
      if (l15 == 0) {
        st[h][quad * 4 + r][wave][0] = m;  st[h][quad * 4 + r][wave][1] = z;
        st[h][quad * 4 + r][wave][2] = s2; st[h][quad * 4 + r][wave][3] = mnv;
      }
    }
  __syncthreads();
  if (tid < 32) {
    int row = tid & 15, h = tid >> 4;
    float Mf = -1e30f, mnf = 1e30f;
    for (int w = 0; w < 4; w++) { Mf = fmaxf(Mf, st[h][row][w][0]); mnf = fminf(mnf, st[h][row][w][3]); }
    float Z = 0.f, S2 = 0.f;
    for (int w = 0; w < 4; w++) {
      float f = expf(st[h][row][w][0] - Mf);
      Z += st[h][row][w][1] * f; S2 += st[h][row][w][2] * f * f;
    }
    float* o = rowstats + ((long)pair * 512 + t0 + row) * 8 + h * 4;
    o[0] = Mf; o[1] = Z; o[2] = S2; o[3] = mnf;
    fin[h][row][0] = Mf; fin[h][row][1] = 1.0f / Z;
  }
  __syncthreads();
  // ---- p -> LDS as bf16, A-fragment-friendly layout ----
  u16* pbuf = (u16*)fbig;   // [h][wave][row16][136]
#pragma unroll
  for (int h = 0; h < 2; h++)
#pragma unroll
    for (int r = 0; r < 4; r++) {
      int row = quad * 4 + r;
      float Mf = fin[h][row][0], iZ = fin[h][row][1];
#pragma unroll
      for (int ct = 0; ct < 8; ct++) {
        float p = expf(sc[h][ct][r] - Mf) * iZ;
        pbuf[((h * 4 + wave) * 16 + row) * 136 + ct * 16 + l15] = f2b(p);
      }
    }
  __syncthreads();
  // ---- Phase B: ob_w[16x64] = p_w[16x128] @ v[128x64] (per wave s-range) ----
  f32x4 acc[2][4];
#pragma unroll
  for (int h = 0; h < 2; h++)
#pragma unroll
    for (int nt = 0; nt < 4; nt++) acc[h][nt] = {0.f, 0.f, 0.f, 0.f};
  const u16* vThb = vTh + (long)pair * 64 * 512;
  const u16* vTlb = vTl + (long)pair * 64 * 512;
#pragma unroll
  for (int kc = 0; kc < 4; kc++) {
    int sbase = wave * 128 + kc * 32 + quad * 8;
    bf16x8 A0 = *(const bf16x8*)(pbuf + ((0 * 4 + wave) * 16 + l15) * 136 + kc * 32 + quad * 8);
    bf16x8 A1 = *(const bf16x8*)(pbuf + ((1 * 4 + wave) * 16 + l15) * 136 + kc * 32 + quad * 8);
#pragma unroll
    for (int nt = 0; nt < 4; nt++) {
      long vo = (long)(nt * 16 + l15) * 512 + sbase;
      bf16x8 Vh = *(const bf16x8*)(vThb + vo);
      bf16x8 Vl = *(const bf16x8*)(vTlb + vo);
      acc[0][nt] = __builtin_amdgcn_mfma_f32_16x16x32_bf16(A0, Vh, acc[0][nt], 0, 0, 0);
      acc[0][nt] = __builtin_amdgcn_mfma_f32_16x16x32_bf16(A0, Vl, acc[0][nt], 0, 0, 0);
      acc[1][nt] = __builtin_amdgcn_mfma_f32_16x16x32_bf16(A1, Vh, acc[1][nt], 0, 0, 0);
      acc[1][nt] = __builtin_amdgcn_mfma_f32_16x16x32_bf16(A1, Vl, acc[1][nt], 0, 0, 0);
    }
  }
  __syncthreads();   // done reading pbuf; reuse as obr
  float* obr = fbig; // [wave][h][row16][68]
#pragma unroll
  for (int h = 0; h < 2; h++)
#pragma unroll
    for (int nt = 0; nt < 4; nt++)
#pragma unroll
      for (int r = 0; r < 4; r++)
        obr[((wave * 2 + h) * 16 + quad * 4 + r) * 68 + nt * 16 + l15] = acc[h][nt][r];
  __syncthreads();
  for (int i = tid; i < 2048; i += 256) {
    int h = i >> 10, row = (i >> 6) & 15, d = i & 63;
    float s = 0.f;
    for (int w = 0; w < 4; w++) s += obr[((w * 2 + h) * 16 + row) * 68 + d];
    float* dst = (h == 0 ? ob1 : ob2);
    dst[((long)pair * 512 + t0 + row) * 64 + d] = s;
  }
}

// ---------------- Stage 1c: matrix stats -> lambda MLP ----------------
__global__ __launch_bounds__(64) void k_lam(const float* rowstats, fp lw1, fp lb1,
                                            fp lw2, fp lb2, float* lam) {
  int pair = blockIdx.x; int kb = pair >> 2;
  int tid = threadIdx.x;
  const float* rs = rowstats + (long)pair * 512 * 8;
  float mx1 = -1e30f, mn1 = 1e30f, ss1 = 0.f, mx2 = -1e30f, mn2 = 1e30f, ss2 = 0.f;
  for (int j = 0; j < 8; j++) {
    const float* rr = rs + (long)(j * 64 + tid) * 8;
    float M1 = rr[0], Z1 = rr[1], S21 = rr[2], m1 = rr[3];
    float M2 = rr[4], Z2 = rr[5], S22 = rr[6], m2 = rr[7];
    mx1 = fmaxf(mx1, 1.0f / Z1); mn1 = fminf(mn1, expf(m1 - M1) / Z1); ss1 += S21 / (Z1 * Z1);
    mx2 = fmaxf(mx2, 1.0f / Z2); mn2 = fminf(mn2, expf(m2 - M2) / Z2); ss2 += S22 / (Z2 * Z2);
  }
  __shared__ float red[64][8];
  red[tid][0] = mx1; red[tid][1] = mn1; red[tid][2] = ss1;
  red[tid][3] = mx2; red[tid][4] = mn2; red[tid][5] = ss2;
  __syncthreads();
  if (tid == 0) {
    for (int e = 1; e < 64; e++) {
      mx1 = fmaxf(mx1, red[e][0]); mn1 = fminf(mn1, red[e][1]); ss1 += red[e][2];
      mx2 = fmaxf(mx2, red[e][3]); mn2 = fminf(mn2, red[e][4]); ss2 += red[e][5];
    }
    const float mean = 1.0f / 512.0f;
    const float n = 262144.0f;
    float v1 = (ss1 - n * mean * mean) / (n - 1.0f); float sd1 = sqrtf(fmaxf(v1, 0.f));
    float v2 = (ss2 - n * mean * mean) / (n - 1.0f); float sd2 = sqrtf(fmaxf(v2, 0.f));
    float stv[8] = { mean, sd1, mx1, mn1, mean, sd2, mx2, mn2 };
    float acc = lb2[kb];
    for (int o = 0; o < 16; o++) {
      float h = lb1[kb * 16 + o];
      for (int i = 0; i < 8; i++) h += stv[i] * lw1[(kb * 8 + i) * 16 + o];
      h = fmaxf(h, 0.f);
      acc += h * lw2[kb * 16 + o];
    }
    lam[pair] = 1.0f / (1.0f + expf(-acc));
  }
}

// ---------------- Stage 1d: epilogue h1 = (ob1 - lam*ob2)@Wo + bo -------------
// h1 layout [B][K][T][N]
__global__ __launch_bounds__(128) void k_ep(const float* ob1, const float* ob2,
                                            const float* lam, fp Wo, fp bo, float* h1) {
  int pair = blockIdx.y; int kb = pair >> 2, b = pair & 3;
  int t0 = blockIdx.x * 8;
  int tid = threadIdx.x;
  float lv = lam[pair];
  __shared__ float obs[8][68];
  for (int i = tid; i < 512; i += 128) {
    int r = i >> 6, d = i & 63;
    long o = ((long)pair * 512 + t0 + r) * 64 + d;
    obs[r][d] = ob1[o] - lv * ob2[o];
  }
  __syncthreads();
  int n = tid;
  float acc[8];
#pragma unroll
  for (int r = 0; r < 8; r++) acc[r] = bo[kb * 128 + n];
  for (int dd = 0; dd < 64; dd++) {
    float w = Wo[(kb * 64 + dd) * 128 + n];
#pragma unroll
    for (int r = 0; r < 8; r++) acc[r] += obs[r][dd] * w;
  }
#pragma unroll
  for (int r = 0; r < 8; r++)
    h1[((long)(b * 30 + kb) * 512 + t0 + r) * 128 + n] = acc[r];
}

// ---------------- Stage 2a: combined per-band conv kernel ----------------
// ck layout [k][ni][r(32)][no], r index = signed offset + 16; split ckA/ckB
__global__ __launch_bounds__(256) void k_ck(fp fw, fp cw2, fp cw4, fp cw8,
                                            fp cw16, fp cw32, float* ckA, float* ckB) {
  int idx = blockIdx.x * 256 + threadIdx.x;
  int no = idx & 127;
  int r = (idx >> 7) & 31;
  int ni = (idx >> 12) & 127;
  int kb = idx >> 19;
  float f0 = fw[kb * 3 + 0], f1 = fw[kb * 3 + 1], f2 = fw[kb * 3 + 2];
  float mx = fmaxf(f0, fmaxf(f1, f2));
  float e0 = expf(f0 - mx), e1 = expf(f1 - mx), e2 = expf(f2 - mx);
  float zi = 1.0f / (e0 + e1 + e2);
  float sw[3] = { e0 * zi, e1 * zi, e2 * zi };
  int sbase; fp cws[3];
  if (kb < 6)       { sbase = 8; cws[0] = cw8;  cws[1] = cw16; cws[2] = cw32; }
  else if (kb < 15) { sbase = 4; cws[0] = cw4;  cws[1] = cw8;  cws[2] = cw16; }
  else              { sbase = 2; cws[0] = cw2;  cws[1] = cw4;  cws[2] = cw8;  }
  float val = 0.f;
  int rs = r - 16;
#pragma unroll
  for (int j = 0; j < 3; j++) {
    int s = sbase << j;
    int tau = rs + (s >> 1);
    if (tau >= 0 && tau < s) val += sw[j] * cws[j][((long)no * 128 + ni) * s + tau];
  }
  int lidx = idx & 524287;
  float* dst = (kb < 15) ? (ckA + (long)kb * 524288 + lidx)
                         : (ckB + (long)(kb - 15) * 524288 + lidx);
  *dst = val;
}

// ---------------- Stage 2b: per-band conv, h1 -> h2 ----------------
// h1 [B][K][T][N]; h2 [B][T][K][N]
__global__ __launch_bounds__(256) void k_conv(const float* h1, const float* ckA,
                                              const float* ckB, fp fw,
                                              fp cb2, fp cb4, fp cb8, fp cb16,
                                              fp cb32, float* h2) {
  int kb = blockIdx.z, b = blockIdx.y, t0 = blockIdx.x * 64;
  int tid = threadIdx.x;
  __shared__ float xs[128][97];
  const float* xrow = h1 + (long)(b * 30 + kb) * 512 * 128;
  for (int idx = tid; idx < 96 * 128; idx += 256) {
    int col = idx >> 7, n = idx & 127;
    int t = t0 - 16 + col;
    xs[n][col] = (t >= 0 && t < 512) ? xrow[(long)t * 128 + n] : 0.f;
  }
  int ng = tid & 15, tg = tid >> 4;
  float f0 = fw[kb * 3 + 0], f1 = fw[kb * 3 + 1], f2 = fw[kb * 3 + 2];
  float mx = fmaxf(f0, fmaxf(f1, f2));
  float e0 = expf(f0 - mx), e1 = expf(f1 - mx), e2 = expf(f2 - mx);
  float zi = 1.0f / (e0 + e1 + e2);
  int rlo, rhi; fp c0, c1, c2;
  if (kb < 6)       { rlo = 0;  rhi = 32; c0 = cb8; c1 = cb16; c2 = cb32; }
  else if (kb < 15) { rlo = 8;  rhi = 24; c0 = cb4; c1 = cb8;  c2 = cb16; }
  else              { rlo = 12; rhi = 20; c0 = cb2; c1 = cb4;  c2 = cb8;  }
  float acc[8][4];
#pragma unroll
  for (int j = 0; j < 8; j++) {
    float cb = e0 * zi * c0[ng * 8 + j] + e1 * zi * c1[ng * 8 + j]
             + e2 * zi * c2[ng * 8 + j];
#pragma unroll
    for (int i = 0; i < 4; i++) acc[j][i] = cb;
  }
  __syncthreads();
  const float* ckb = (kb < 15) ? (ckA + (long)kb * 524288)
                               : (ckB + (long)(kb - 15) * 524288);
  int toff = tg * 4;
  for (int ni = 0; ni < 128; ni++) {
    const float* xr0 = &xs[ni][toff];
    for (int r = rlo; r < rhi; r++) {
      float4 w0 = *(const float4*)&ckb[(ni * 32 + r) * 128 + ng * 8];
      float4 w1 = *(const float4*)&ckb[(ni * 32 + r) * 128 + ng * 8 + 4];
      float xv0 = xr0[r + 0], xv1 = xr0[r + 1], xv2 = xr0[r + 2], xv3 = xr0[r + 3];
      float wj[8] = { w0.x, w0.y, w0.z, w0.w, w1.x, w1.y, w1.z, w1.w };
#pragma unroll
      for (int j = 0; j < 8; j++) {
        acc[j][0] += wj[j] * xv0; acc[j][1] += wj[j] * xv1;
        acc[j][2] += wj[j] * xv2; acc[j][3] += wj[j] * xv3;
      }
    }
  }
#pragma unroll
  for (int i = 0; i < 4; i++) {
    long ob = ((long)(b * 512 + t0 + toff + i) * 30 + kb) * 128 + ng * 8;
    float4 s0 = { acc[0][i], acc[1][i], acc[2][i], acc[3][i] };
    float4 s1 = { acc[4][i], acc[5][i], acc[6][i], acc[7][i] };
    *(float4*)&h2[ob] = s0;
    *(float4*)&h2[ob + 4] = s1;
  }
}

// ---------------- Stage 3a: graph QKV ----------------
__global__ __launch_bounds__(128) void k_gqkv(const float* h2, fp gWq, fp gbq,
                                              fp gWk, fp gbk, fp gWv, fp gbv,
                                              float* qg, float* kg, float* vg) {
  long row0 = (long)blockIdx.x * 16;
  int m = threadIdx.x;
  __shared__ float xs[16][132];
  for (int idx = m; idx < 16 * 128; idx += 128) {
    int r = idx >> 7, c = idx & 127;
    xs[r][c] = h2[(row0 + r) * 128 + c];
  }
  __syncthreads();
  float aq[16], ak[16], av[16];
#pragma unroll
  for (int r = 0; r < 16; r++) { aq[r] = 0.f; ak[r] = 0.f; av[r] = 0.f; }
  for (int n = 0; n < 128; n++) {
    float wq = gWq[n * 128 + m], wk = gWk[n * 128 + m], wv = gWv[n * 128 + m];
#pragma unroll
    for (int r = 0; r < 16; r++) {
      float xv = xs[r][n];
      aq[r] += xv * wq; ak[r] += xv * wk; av[r] += xv * wv;
    }
  }
  float bq = gbq[m], bk = gbk[m], bv = gbv[m];
#pragma unroll
  for (int r = 0; r < 16; r++) {
    qg[(row0 + r) * 128 + m] = aq[r] + bq;
    kg[(row0 + r) * 128 + m] = ak[r] + bk;
    vg[(row0 + r) * 128 + m] = av[r] + bv;
  }
}

// ---------------- Stage 3b: graph attention + output GEMM ----------------
__global__ __launch_bounds__(128) void k_gattn(const float* qg, const float* kg,
                                               const float* vg, const float* maskw,
                                               fp gWo, fp gbo, float* out) {
  int m = blockIdx.x; int b = m >> 9; int t = m & 511;
  int tid = threadIdx.x;
  __shared__ float qs[30][132];
  __shared__ float ks[30][132];
  __shared__ float vs[30][132];
  __shared__ float msk[30][32];
  float (*ogs)[132] = qs;
  const float* qb = qg + (long)m * 30 * 128;
  const float* kb2 = kg + (long)m * 30 * 128;
  const float* vb2 = vg + (long)m * 30 * 128;
  for (int idx = tid; idx < 3840; idx += 128) {
    int j = idx >> 7, n = idx & 127;
    qs[j][n] = qb[idx]; ks[j][n] = kb2[idx]; vs[j][n] = vb2[idx];
  }
  for (int idx = tid; idx < 900; idx += 128) msk[idx / 30][idx % 30] = maskw[idx];
  __syncthreads();
  float p[30]; float iZ = 0.f; int hi = 0, ii = 0;
  if (tid < 120) {
    hi = tid / 30; ii = tid % 30;
    int hb = hi * 32;
    float4 qv[8];
#pragma unroll
    for (int dq = 0; dq < 8; dq++) qv[dq] = *(const float4*)&qs[ii][hb + dq * 4];
    float mx = -1e30f;
#pragma unroll
    for (int j = 0; j < 30; j++) {
      float s = 0.f;
      const float4* kr = (const float4*)&ks[j][hb];
#pragma unroll
      for (int dq = 0; dq < 8; dq++) {
        float4 kv = kr[dq];
        s += qv[dq].x * kv.x + qv[dq].y * kv.y + qv[dq].z * kv.z + qv[dq].w * kv.w;
      }
      s *= 0.17677669529663687f;
      p[j] = (msk[ii][j] != 0.f) ? s : -1e30f;
      mx = fmaxf(mx, p[j]);
    }
    float Z = 0.f;
#pragma unroll
    for (int j = 0; j < 30; j++) { float e = expf(p[j] - mx); p[j] = e; Z += e; }
    iZ = 1.0f / Z;
  }
  __syncthreads();
  if (tid < 120) {
    int hb = hi * 32;
#pragma unroll
    for (int dq = 0; dq < 8; dq++) {
      float sx = 0.f, sy = 0.f, sz = 0.f, sw2 = 0.f;
#pragma unroll
      for (int j = 0; j < 30; j++) {
        float4 vv = *(const float4*)&vs[j][hb + dq * 4];
        sx += p[j] * vv.x; sy += p[j] * vv.y; sz += p[j] * vv.z; sw2 += p[j] * vv.w;
      }
      float4 o = { sx * iZ, sy * iZ, sz * iZ, sw2 * iZ };
      *(float4*)&ogs[ii][hb + dq * 4] = o;
    }
  }
  __syncthreads();
  {
    int n = tid;
    float acc[30];
#pragma unroll
    for (int j = 0; j < 30; j++) acc[j] = 0.f;
    for (int d = 0; d < 128; d += 4) {
      float w0 = gWo[(d + 0) * 128 + n];
      float w1 = gWo[(d + 1) * 128 + n];
      float w2 = gWo[(d + 2) * 128 + n];
      float w3 = gWo[(d + 3) * 128 + n];
#pragma unroll
      for (int j = 0; j < 30; j++) {
        float4 og4 = *(const float4*)&ogs[j][d];
        acc[j] += og4.x * w0 + og4.y * w1 + og4.z * w2 + og4.w * w3;
      }
    }
    float gb = gbo[n];
    float* outp = out + ((long)(b * 128 + n) * 512 + t) * 30;
#pragma unroll
    for (int j = 0; j < 30; j++) outp[j] = acc[j] + gb;
  }
}

extern "C" void kernel_launch(void* const* d_in, const int* in_sizes, int n_in,
                              void* d_out, int out_size, void* d_ws, size_t ws_size,
                              hipStream_t stream) {
  fp x = (fp)d_in[0], Wq = (fp)d_in[1], Wk = (fp)d_in[2], Wv = (fp)d_in[3],
     Wo = (fp)d_in[4], bo = (fp)d_in[5], lw1 = (fp)d_in[6], lb1 = (fp)d_in[7],
     lw2 = (fp)d_in[8], lb2 = (fp)d_in[9],
     cw2 = (fp)d_in[10], cb2 = (fp)d_in[11], cw4 = (fp)d_in[12], cb4 = (fp)d_in[13],
     cw8 = (fp)d_in[14], cb8 = (fp)d_in[15], cw16 = (fp)d_in[16], cb16 = (fp)d_in[17],
     cw32 = (fp)d_in[18], cb32 = (fp)d_in[19], fw = (fp)d_in[20], be = (fp)d_in[21],
     gWq = (fp)d_in[22], gbq = (fp)d_in[23], gWk = (fp)d_in[24], gbk = (fp)d_in[25],
     gWv = (fp)d_in[26], gbv = (fp)d_in[27], gWo = (fp)d_in[28], gbo = (fp)d_in[29];
  (void)in_sizes; (void)n_in; (void)out_size; (void)ws_size;

  float* ws = (float*)d_ws;
  // ---- workspace map (float offsets), with stage-ordered aliasing ----
  // 0         .. 3,932,160 : qh (bf16 [120][512][128]) -> later ob1 (f32 [120][512][64]) -> ckA -> qg
  // 3,932,160 .. 7,864,320 : ql -> ob2 (exact same span)
  // 7,864,320 ..11,796,480 : kh -> h2 (spans kh+kl)
  // 11,796,480..15,728,640 : kl
  // 15,728,640..17,694,720 : vTh (bf16 [120][64][512]) -> ckB (spans to 23,592,960) -> kg
  // 17,694,720..19,660,800 : vTl
  // 19,660,800..20,152,320 : rowstats [120][512][8]
  // 20,152,320..20,152,448 : lam
  // 23,592,960..31,457,280 : h1 -> vg
  // 31,457,280..31,458,304 : mask
  u16* qh  = (u16*)ws;
  u16* ql  = (u16*)(ws + 3932160L);
  u16* kh  = (u16*)(ws + 7864320L);
  u16* kl  = (u16*)(ws + 11796480L);
  u16* vTh = (u16*)(ws + 15728640L);
  u16* vTl = (u16*)(ws + 17694720L);
  float* rowstats = ws + 19660800L;
  float* lam      = ws + 20152320L;
  float* ob1 = ws;
  float* ob2 = ws + 3932160L;
  float* h1  = ws + 23592960L;
  float* ckA = ws;                  // 15 bands (after k_ep; ob dead)
  float* ckB = ws + 15728640L;      // 15 bands (vT/rowstats/lam dead)
  float* h2  = ws + 7864320L;       // over kh+kl
  float* qg  = ws;                  // stage 3
  float* kg  = ws + 15728640L;
  float* vg  = ws + 23592960L;
  float* maskw = ws + 31457280L;

  k_adj<<<1, 64, 0, stream>>>(be, maskw);
  k_qkv<<<dim3(64, 4, 30), 128, 0, stream>>>(x, Wq, Wk, Wv, qh, ql, kh, kl, vTh, vTl);
  k_flash<<<dim3(32, 120), 256, 0, stream>>>(qh, ql, kh, kl, vTh, vTl, rowstats, ob1, ob2);
  k_lam<<<120, 64, 0, stream>>>(rowstats, lw1, lb1, lw2, lb2, lam);
  k_ep<<<dim3(64, 120), 128, 0, stream>>>(ob1, ob2, lam, Wo, bo, h1);
  k_ck<<<61440, 256, 0, stream>>>(fw, cw2, cw4, cw8, cw16, cw32, ckA, ckB);
  k_conv<<<dim3(8, 4, 30), 256, 0, stream>>>(h1, ckA, ckB, fw, cb2, cb4, cb8, cb16, cb32, h2);
  k_gqkv<<<3840, 128, 0, stream>>>(h2, gWq, gbq, gWk, gbk, gWv, gbv, qg, kg, vg);
  k_gattn<<<2048, 128, 0, stream>>>(qg, kg, vg, maskw, gWo, gbo, (float*)d_out);
}

// Round 4
// 966.929 us; speedup vs baseline: 2.9568x; 1.5621x over previous
//
#include <hip/hip_runtime.h>

// Problem constants: B=4, N=128, T=512, K=30 bands. All I/O fp32.
typedef const float* fp;
typedef unsigned short u16;
typedef __attribute__((ext_vector_type(8))) short bf16x8;   // 8 bf16 = 4 VGPRs
typedef __attribute__((ext_vector_type(4))) float f32x4;

__device__ __forceinline__ u16 f2b(float f) {
  union { float f; unsigned u; } a; a.f = f;
  unsigned u = a.u;
  u += 0x7fffu + ((u >> 16) & 1u);   // RNE
  return (u16)(u >> 16);
}
// split fp32 into hi (truncated bf16) + lo (RNE bf16 of exact remainder)
__device__ __forceinline__ void splitf(float x, u16& h, u16& l) {
  union { float f; unsigned u; } a; a.f = x;
  unsigned hu = a.u & 0xFFFF0000u;
  h = (u16)(hu >> 16);
  union { unsigned u; float f; } b; b.u = hu;
  l = f2b(x - b.f);
}

// ---------------- Stage 0: adjacency mask from band embeddings ----------------
__global__ __launch_bounds__(64) void k_adj(fp be, float* mask) {
  __shared__ float e[30][65];
  __shared__ float sim[30][33];
  __shared__ float A[30][33];
  int tid = threadIdx.x;
  for (int idx = tid; idx < 30 * 64; idx += 64) e[idx / 64][idx % 64] = be[idx];
  __syncthreads();
  if (tid < 30) {
    float s = 0.f;
    for (int d = 0; d < 64; d++) s += e[tid][d] * e[tid][d];
    float sc = 1.0f / (sqrtf(s) + 1e-8f);
    for (int d = 0; d < 64; d++) e[tid][d] *= sc;
  }
  __syncthreads();
  if (tid < 30) {
    for (int j = 0; j < 30; j++) {
      float s = 0.f;
      for (int d = 0; d < 64; d++) s += e[tid][d] * e[j][d];
      sim[tid][j] = s;
    }
    for (int j = 0; j < 30; j++) A[tid][j] = 0.f;
  }
  __syncthreads();
  if (tid < 30) {
    unsigned used = 0;
    for (int t = 0; t < 5; t++) {
      float best = -1e30f; int bi = 0;
      for (int j = 0; j < 30; j++)
        if (!((used >> j) & 1u) && sim[tid][j] > best) { best = sim[tid][j]; bi = j; }
      A[tid][bi] = best; used |= 1u << bi;
    }
  }
  __syncthreads();
  for (int idx = tid; idx < 900; idx += 64) {
    int i = idx / 30, j = idx % 30;
    float s = A[i][j] + A[j][i];
    mask[idx] = (s != 0.0f) ? 1.0f : 0.0f;
  }
}

// ---------------- Stage 1a: per-band QKV projections (split-bf16 out) ---------
__global__ __launch_bounds__(128) void k_qkv(fp x, fp Wq, fp Wk, fp Wv,
                                             u16* qh, u16* ql, u16* kh, u16* kl,
                                             u16* vTh, u16* vTl) {
  int kb = blockIdx.z, b = blockIdx.y, t0 = blockIdx.x * 8;
  int tid = threadIdx.x;
  __shared__ float xs[8][129];
  for (int idx = tid; idx < 8 * 128; idx += 128) {
    int r = idx >> 7, n = idx & 127;
    xs[r][n] = x[((long)(b * 128 + n) * 512 + (t0 + r)) * 30 + kb];
  }
  __syncthreads();
  int m = tid;
  float aq[8], ak[8], av[8];
#pragma unroll
  for (int r = 0; r < 8; r++) { aq[r] = 0.f; ak[r] = 0.f; av[r] = 0.f; }
  for (int n = 0; n < 128; n++) {
    float wq = Wq[(kb * 128 + n) * 128 + m];
    float wk = Wk[(kb * 128 + n) * 128 + m];
    float wv = (m < 64) ? Wv[(kb * 128 + n) * 64 + m] : 0.f;
#pragma unroll
    for (int r = 0; r < 8; r++) {
      float xv = xs[r][n];
      aq[r] += xv * wq; ak[r] += xv * wk; av[r] += xv * wv;
    }
  }
  int pair = kb * 4 + b;
  long base = (long)pair * 512 + t0;
#pragma unroll
  for (int r = 0; r < 8; r++) {
    u16 hh, ll;
    splitf(aq[r], hh, ll); qh[(base + r) * 128 + m] = hh; ql[(base + r) * 128 + m] = ll;
    splitf(ak[r], hh, ll); kh[(base + r) * 128 + m] = hh; kl[(base + r) * 128 + m] = ll;
    if (m < 64) {
      splitf(av[r], hh, ll);
      long vo = ((long)pair * 64 + m) * 512 + t0 + r;
      vTh[vo] = hh; vTl[vo] = ll;
    }
  }
}

// ---------------- Stage 1b: fused flash kernel ----------------
__global__ __launch_bounds__(256) void k_flash(const u16* qh, const u16* ql,
                                               const u16* kh, const u16* kl,
                                               const u16* vTh, const u16* vTl,
                                               float* rowstats, float* ob1, float* ob2) {
  int pair = blockIdx.y;
  int t0 = blockIdx.x * 16;
  int tid = threadIdx.x;
  int wave = tid >> 6, lane = tid & 63;
  int l15 = lane & 15, quad = lane >> 4;

  __shared__ float fbig[8704];
  __shared__ float st[2][16][4][4];
  __shared__ float fin[2][16][2];

  const long pb = (long)pair * 512 * 128;
  const u16* qhb = qh + pb; const u16* qlb = ql + pb;
  const u16* khb = kh + pb; const u16* klb = kl + pb;

  float sc[2][8][4];
#pragma unroll
  for (int h = 0; h < 2; h++) {
    long abase = (long)(t0 + l15) * 128 + h * 64 + quad * 8;
    bf16x8 Ah0 = *(const bf16x8*)(qhb + abase);
    bf16x8 Ah1 = *(const bf16x8*)(qhb + abase + 32);
    bf16x8 Al0 = *(const bf16x8*)(qlb + abase);
    bf16x8 Al1 = *(const bf16x8*)(qlb + abase + 32);
#pragma unroll
    for (int ct = 0; ct < 8; ct++) {
      int scol = wave * 128 + ct * 16 + l15;
      long bbase = (long)scol * 128 + h * 64 + quad * 8;
      bf16x8 Bh0 = *(const bf16x8*)(khb + bbase);
      bf16x8 Bh1 = *(const bf16x8*)(khb + bbase + 32);
      bf16x8 Bl0 = *(const bf16x8*)(klb + bbase);
      bf16x8 Bl1 = *(const bf16x8*)(klb + bbase + 32);
      f32x4 d = {0.f, 0.f, 0.f, 0.f};
      d = __builtin_amdgcn_mfma_f32_16x16x32_bf16(Ah0, Bh0, d, 0, 0, 0);
      d = __builtin_amdgcn_mfma_f32_16x16x32_bf16(Ah1, Bh1, d, 0, 0, 0);
      d = __builtin_amdgcn_mfma_f32_16x16x32_bf16(Ah0, Bl0, d, 0, 0, 0);
      d = __builtin_amdgcn_mfma_f32_16x16x32_bf16(Ah1, Bl1, d, 0, 0, 0);
      d = __builtin_amdgcn_mfma_f32_16x16x32_bf16(Al0, Bh0, d, 0, 0, 0);
      d = __builtin_amdgcn_mfma_f32_16x16x32_bf16(Al1, Bh1, d, 0, 0, 0);
#pragma unroll
      for (int r = 0; r < 4; r++) sc[h][ct][r] = d[r] * 0.25f;
    }
  }
#pragma unroll
  for (int h = 0; h < 2; h++)
#pragma unroll
    for (int r = 0; r < 4; r++) {
      float m = -1e30f, mnv = 1e30f;
#pragma unroll
      for (int ct = 0; ct < 8; ct++) { m = fmaxf(m, sc[h][ct][r]); mnv = fminf(mnv, sc[h][ct][r]); }
      for (int d = 1; d < 16; d <<= 1) { m = fmaxf(m, __shfl_xor(m, d)); mnv = fminf(mnv, __shfl_xor(mnv, d)); }
      float z = 0.f, s2 = 0.f;
#pragma unroll
      for (int ct = 0; ct < 8; ct++) { float e = expf(sc[h][ct][r] - m); z += e; s2 += e * e; }
      for (int d = 1; d < 16; d <<= 1) { z += __shfl_xor(z, d); s2 += __shfl_xor(s2, d); }
      if (l15 == 0) {
        st[h][quad * 4 + r][wave][0] = m;  st[h][quad * 4 + r][wave][1] = z;
        st[h][quad * 4 + r][wave][2] = s2; st[h][quad * 4 + r][wave][3] = mnv;
      }
    }
  __syncthreads();
  if (tid < 32) {
    int row = tid & 15, h = tid >> 4;
    float Mf = -1e30f, mnf = 1e30f;
    for (int w = 0; w < 4; w++) { Mf = fmaxf(Mf, st[h][row][w][0]); mnf = fminf(mnf, st[h][row][w][3]); }
    float Z = 0.f, S2 = 0.f;
    for (int w = 0; w < 4; w++) {
      float f = expf(st[h][row][w][0] - Mf);
      Z += st[h][row][w][1] * f; S2 += st[h][row][w][2] * f * f;
    }
    float* o = rowstats + ((long)pair * 512 + t0 + row) * 8 + h * 4;
    o[0] = Mf; o[1] = Z; o[2] = S2; o[3] = mnf;
    fin[h][row][0] = Mf; fin[h][row][1] = 1.0f / Z;
  }
  __syncthreads();
  u16* pbuf = (u16*)fbig;   // [h][wave][row16][136]
#pragma unroll
  for (int h = 0; h < 2; h++)
#pragma unroll
    for (int r = 0; r < 4; r++) {
      int row = quad * 4 + r;
      float Mf = fin[h][row][0], iZ = fin[h][row][1];
#pragma unroll
      for (int ct = 0; ct < 8; ct++) {
        float p = expf(sc[h][ct][r] - Mf) * iZ;
        pbuf[((h * 4 + wave) * 16 + row) * 136 + ct * 16 + l15] = f2b(p);
      }
    }
  __syncthreads();
  f32x4 acc[2][4];
#pragma unroll
  for (int h = 0; h < 2; h++)
#pragma unroll
    for (int nt = 0; nt < 4; nt++) acc[h][nt] = {0.f, 0.f, 0.f, 0.f};
  const u16* vThb = vTh + (long)pair * 64 * 512;
  const u16* vTlb = vTl + (long)pair * 64 * 512;
#pragma unroll
  for (int kc = 0; kc < 4; kc++) {
    int sbase = wave * 128 + kc * 32 + quad * 8;
    bf16x8 A0 = *(const bf16x8*)(pbuf + ((0 * 4 + wave) * 16 + l15) * 136 + kc * 32 + quad * 8);
    bf16x8 A1 = *(const bf16x8*)(pbuf + ((1 * 4 + wave) * 16 + l15) * 136 + kc * 32 + quad * 8);
#pragma unroll
    for (int nt = 0; nt < 4; nt++) {
      long vo = (long)(nt * 16 + l15) * 512 + sbase;
      bf16x8 Vh = *(const bf16x8*)(vThb + vo);
      bf16x8 Vl = *(const bf16x8*)(vTlb + vo);
      acc[0][nt] = __builtin_amdgcn_mfma_f32_16x16x32_bf16(A0, Vh, acc[0][nt], 0, 0, 0);
      acc[0][nt] = __builtin_amdgcn_mfma_f32_16x16x32_bf16(A0, Vl, acc[0][nt], 0, 0, 0);
      acc[1][nt] = __builtin_amdgcn_mfma_f32_16x16x32_bf16(A1, Vh, acc[1][nt], 0, 0, 0);
      acc[1][nt] = __builtin_amdgcn_mfma_f32_16x16x32_bf16(A1, Vl, acc[1][nt], 0, 0, 0);
    }
  }
  __syncthreads();
  float* obr = fbig; // [wave][h][row16][68]
#pragma unroll
  for (int h = 0; h < 2; h++)
#pragma unroll
    for (int nt = 0; nt < 4; nt++)
#pragma unroll
      for (int r = 0; r < 4; r++)
        obr[((wave * 2 + h) * 16 + quad * 4 + r) * 68 + nt * 16 + l15] = acc[h][nt][r];
  __syncthreads();
  for (int i = tid; i < 2048; i += 256) {
    int h = i >> 10, row = (i >> 6) & 15, d = i & 63;
    float s = 0.f;
    for (int w = 0; w < 4; w++) s += obr[((w * 2 + h) * 16 + row) * 68 + d];
    float* dst = (h == 0 ? ob1 : ob2);
    dst[((long)pair * 512 + t0 + row) * 64 + d] = s;
  }
}

// ---------------- Stage 1c: matrix stats -> lambda MLP ----------------
__global__ __launch_bounds__(64) void k_lam(const float* rowstats, fp lw1, fp lb1,
                                            fp lw2, fp lb2, float* lam) {
  int pair = blockIdx.x; int kb = pair >> 2;
  int tid = threadIdx.x;
  const float* rs = rowstats + (long)pair * 512 * 8;
  float mx1 = -1e30f, mn1 = 1e30f, ss1 = 0.f, mx2 = -1e30f, mn2 = 1e30f, ss2 = 0.f;
  for (int j = 0; j < 8; j++) {
    const float* rr = rs + (long)(j * 64 + tid) * 8;
    float M1 = rr[0], Z1 = rr[1], S21 = rr[2], m1 = rr[3];
    float M2 = rr[4], Z2 = rr[5], S22 = rr[6], m2 = rr[7];
    mx1 = fmaxf(mx1, 1.0f / Z1); mn1 = fminf(mn1, expf(m1 - M1) / Z1); ss1 += S21 / (Z1 * Z1);
    mx2 = fmaxf(mx2, 1.0f / Z2); mn2 = fminf(mn2, expf(m2 - M2) / Z2); ss2 += S22 / (Z2 * Z2);
  }
  __shared__ float red[64][8];
  red[tid][0] = mx1; red[tid][1] = mn1; red[tid][2] = ss1;
  red[tid][3] = mx2; red[tid][4] = mn2; red[tid][5] = ss2;
  __syncthreads();
  if (tid == 0) {
    for (int e = 1; e < 64; e++) {
      mx1 = fmaxf(mx1, red[e][0]); mn1 = fminf(mn1, red[e][1]); ss1 += red[e][2];
      mx2 = fmaxf(mx2, red[e][3]); mn2 = fminf(mn2, red[e][4]); ss2 += red[e][5];
    }
    const float mean = 1.0f / 512.0f;
    const float n = 262144.0f;
    float v1 = (ss1 - n * mean * mean) / (n - 1.0f); float sd1 = sqrtf(fmaxf(v1, 0.f));
    float v2 = (ss2 - n * mean * mean) / (n - 1.0f); float sd2 = sqrtf(fmaxf(v2, 0.f));
    float stv[8] = { mean, sd1, mx1, mn1, mean, sd2, mx2, mn2 };
    float acc = lb2[kb];
    for (int o = 0; o < 16; o++) {
      float h = lb1[kb * 16 + o];
      for (int i = 0; i < 8; i++) h += stv[i] * lw1[(kb * 8 + i) * 16 + o];
      h = fmaxf(h, 0.f);
      acc += h * lw2[kb * 16 + o];
    }
    lam[pair] = 1.0f / (1.0f + expf(-acc));
  }
}

// ---------------- Stage 1d: epilogue h1 = (ob1 - lam*ob2)@Wo + bo -------------
__global__ __launch_bounds__(128) void k_ep(const float* ob1, const float* ob2,
                                            const float* lam, fp Wo, fp bo, float* h1) {
  int pair = blockIdx.y; int kb = pair >> 2, b = pair & 3;
  int t0 = blockIdx.x * 8;
  int tid = threadIdx.x;
  float lv = lam[pair];
  __shared__ float obs[8][68];
  for (int i = tid; i < 512; i += 128) {
    int r = i >> 6, d = i & 63;
    long o = ((long)pair * 512 + t0 + r) * 64 + d;
    obs[r][d] = ob1[o] - lv * ob2[o];
  }
  __syncthreads();
  int n = tid;
  float acc[8];
#pragma unroll
  for (int r = 0; r < 8; r++) acc[r] = bo[kb * 128 + n];
  for (int dd = 0; dd < 64; dd++) {
    float w = Wo[(kb * 64 + dd) * 128 + n];
#pragma unroll
    for (int r = 0; r < 8; r++) acc[r] += obs[r][dd] * w;
  }
#pragma unroll
  for (int r = 0; r < 8; r++)
    h1[((long)(b * 30 + kb) * 512 + t0 + r) * 128 + n] = acc[r];
}

// ---------------- Stage 2a: combined per-band conv kernel (split bf16) --------
// layout [kb][r(32)][no(128)][ni(128)], r = signed offset + 16
__global__ __launch_bounds__(256) void k_ck(fp fw, fp cw2, fp cw4, fp cw8,
                                            fp cw16, fp cw32, u16* ckh, u16* ckl) {
  long idx = (long)blockIdx.x * 256 + threadIdx.x;
  int ni = idx & 127;
  int no = (idx >> 7) & 127;
  int r  = (idx >> 14) & 31;
  int kb = idx >> 19;
  float f0 = fw[kb * 3 + 0], f1 = fw[kb * 3 + 1], f2 = fw[kb * 3 + 2];
  float mx = fmaxf(f0, fmaxf(f1, f2));
  float e0 = expf(f0 - mx), e1 = expf(f1 - mx), e2 = expf(f2 - mx);
  float zi = 1.0f / (e0 + e1 + e2);
  float sw[3] = { e0 * zi, e1 * zi, e2 * zi };
  int sbase; fp cws[3];
  if (kb < 6)       { sbase = 8; cws[0] = cw8;  cws[1] = cw16; cws[2] = cw32; }
  else if (kb < 15) { sbase = 4; cws[0] = cw4;  cws[1] = cw8;  cws[2] = cw16; }
  else              { sbase = 2; cws[0] = cw2;  cws[1] = cw4;  cws[2] = cw8;  }
  float val = 0.f;
  int rs = r - 16;
#pragma unroll
  for (int j = 0; j < 3; j++) {
    int s = sbase << j;
    int tau = rs + (s >> 1);
    if (tau >= 0 && tau < s) val += sw[j] * cws[j][((long)no * 128 + ni) * s + tau];
  }
  u16 h, l; splitf(val, h, l);
  ckh[idx] = h; ckl[idx] = l;
}

// ---------------- Stage 2b: per-band conv via MFMA, h1 -> h2 ----------------
// h1 [B][K][T][N]; h2 [B][T][K][N]
__global__ __launch_bounds__(256) void k_conv(const float* h1, const u16* ckh,
                                              const u16* ckl, fp fw,
                                              fp cb2, fp cb4, fp cb8, fp cb16,
                                              fp cb32, float* h2) {
  int kb = blockIdx.z, b = blockIdx.y, t0 = blockIdx.x * 64;
  int tid = threadIdx.x;
  int wave = tid >> 6, lane = tid & 63, l15 = lane & 15, quad = lane >> 4;
  __shared__ u16 xs_h[96 * 136];
  __shared__ u16 xs_l[96 * 136];
  const float* xrow = h1 + (long)(b * 30 + kb) * 512 * 128;
  for (int i = tid; i < 3072; i += 256) {
    int row = i >> 5, c4 = (i & 31) << 2;
    int t = t0 - 16 + row;
    float4 xv = {0.f, 0.f, 0.f, 0.f};
    if (t >= 0 && t < 512) xv = *(const float4*)(xrow + (long)t * 128 + c4);
    u16 h, l;
    splitf(xv.x, h, l); xs_h[row * 136 + c4 + 0] = h; xs_l[row * 136 + c4 + 0] = l;
    splitf(xv.y, h, l); xs_h[row * 136 + c4 + 1] = h; xs_l[row * 136 + c4 + 1] = l;
    splitf(xv.z, h, l); xs_h[row * 136 + c4 + 2] = h; xs_l[row * 136 + c4 + 2] = l;
    splitf(xv.w, h, l); xs_h[row * 136 + c4 + 3] = h; xs_l[row * 136 + c4 + 3] = l;
  }
  float f0 = fw[kb * 3 + 0], f1 = fw[kb * 3 + 1], f2 = fw[kb * 3 + 2];
  float mx = fmaxf(f0, fmaxf(f1, f2));
  float e0 = expf(f0 - mx), e1 = expf(f1 - mx), e2 = expf(f2 - mx);
  float zi = 1.0f / (e0 + e1 + e2);
  float sw0 = e0 * zi, sw1 = e1 * zi, sw2 = e2 * zi;
  int rlo, rhi; fp c0, c1, c2;
  if (kb < 6)       { rlo = 0;  rhi = 32; c0 = cb8; c1 = cb16; c2 = cb32; }
  else if (kb < 15) { rlo = 8;  rhi = 24; c0 = cb4; c1 = cb8;  c2 = cb16; }
  else              { rlo = 12; rhi = 20; c0 = cb2; c1 = cb4;  c2 = cb8;  }
  __syncthreads();
  f32x4 acc[4][2];
#pragma unroll
  for (int mt = 0; mt < 4; mt++) { acc[mt][0] = {0.f,0.f,0.f,0.f}; acc[mt][1] = {0.f,0.f,0.f,0.f}; }
  for (int r = rlo; r < rhi; r++) {
    const u16* wh = ckh + ((long)(kb * 32 + r) * 128 + wave * 32 + l15) * 128;
    const u16* wl = ckl + ((long)(kb * 32 + r) * 128 + wave * 32 + l15) * 128;
#pragma unroll
    for (int c = 0; c < 4; c++) {
      int koff = c * 32 + quad * 8;
      bf16x8 Bh0 = *(const bf16x8*)(wh + koff);
      bf16x8 Bh1 = *(const bf16x8*)(wh + 2048 + koff);     // +16*128
      bf16x8 Bl0 = *(const bf16x8*)(wl + koff);
      bf16x8 Bl1 = *(const bf16x8*)(wl + 2048 + koff);
#pragma unroll
      for (int mt = 0; mt < 4; mt++) {
        int arow = mt * 16 + l15 + r;
        bf16x8 Ah = *(const bf16x8*)(xs_h + arow * 136 + koff);
        bf16x8 Al = *(const bf16x8*)(xs_l + arow * 136 + koff);
        acc[mt][0] = __builtin_amdgcn_mfma_f32_16x16x32_bf16(Ah, Bh0, acc[mt][0], 0, 0, 0);
        acc[mt][0] = __builtin_amdgcn_mfma_f32_16x16x32_bf16(Ah, Bl0, acc[mt][0], 0, 0, 0);
        acc[mt][0] = __builtin_amdgcn_mfma_f32_16x16x32_bf16(Al, Bh0, acc[mt][0], 0, 0, 0);
        acc[mt][1] = __builtin_amdgcn_mfma_f32_16x16x32_bf16(Ah, Bh1, acc[mt][1], 0, 0, 0);
        acc[mt][1] = __builtin_amdgcn_mfma_f32_16x16x32_bf16(Ah, Bl1, acc[mt][1], 0, 0, 0);
        acc[mt][1] = __builtin_amdgcn_mfma_f32_16x16x32_bf16(Al, Bh1, acc[mt][1], 0, 0, 0);
      }
    }
  }
  int no0 = wave * 32 + l15;
  float bias0 = sw0 * c0[no0] + sw1 * c1[no0] + sw2 * c2[no0];
  float bias1 = sw0 * c0[no0 + 16] + sw1 * c1[no0 + 16] + sw2 * c2[no0 + 16];
#pragma unroll
  for (int mt = 0; mt < 4; mt++)
#pragma unroll
    for (int reg = 0; reg < 4; reg++) {
      int t = t0 + mt * 16 + quad * 4 + reg;
      long ob = ((long)(b * 512 + t) * 30 + kb) * 128 + no0;
      h2[ob] = acc[mt][0][reg] + bias0;
      h2[ob + 16] = acc[mt][1][reg] + bias1;
    }
}

// ---------------- Stage 3a: graph QKV ----------------
__global__ __launch_bounds__(128) void k_gqkv(const float* h2, fp gWq, fp gbq,
                                              fp gWk, fp gbk, fp gWv, fp gbv,
                                              float* qg, float* kg, float* vg) {
  long row0 = (long)blockIdx.x * 16;
  int m = threadIdx.x;
  __shared__ float xs[16][132];
  for (int idx = m; idx < 16 * 128; idx += 128) {
    int r = idx >> 7, c = idx & 127;
    xs[r][c] = h2[(row0 + r) * 128 + c];
  }
  __syncthreads();
  float aq[16], ak[16], av[16];
#pragma unroll
  for (int r = 0; r < 16; r++) { aq[r] = 0.f; ak[r] = 0.f; av[r] = 0.f; }
  for (int n = 0; n < 128; n++) {
    float wq = gWq[n * 128 + m], wk = gWk[n * 128 + m], wv = gWv[n * 128 + m];
#pragma unroll
    for (int r = 0; r < 16; r++) {
      float xv = xs[r][n];
      aq[r] += xv * wq; ak[r] += xv * wk; av[r] += xv * wv;
    }
  }
  float bq = gbq[m], bk = gbk[m], bv = gbv[m];
#pragma unroll
  for (int r = 0; r < 16; r++) {
    qg[(row0 + r) * 128 + m] = aq[r] + bq;
    kg[(row0 + r) * 128 + m] = ak[r] + bk;
    vg[(row0 + r) * 128 + m] = av[r] + bv;
  }
}

// ---------------- Stage 3b: graph attention + output GEMM ----------------
__global__ __launch_bounds__(128) void k_gattn(const float* qg, const float* kg,
                                               const float* vg, const float* maskw,
                                               fp gWo, fp gbo, float* out) {
  int m = blockIdx.x; int b = m >> 9; int t = m & 511;
  int tid = threadIdx.x;
  __shared__ float qs[30][132];
  __shared__ float ks[30][132];
  __shared__ float vs[30][132];
  __shared__ float msk[30][32];
  float (*ogs)[132] = qs;
  const float* qb = qg + (long)m * 30 * 128;
  const float* kb2 = kg + (long)m * 30 * 128;
  const float* vb2 = vg + (long)m * 30 * 128;
  for (int idx = tid; idx < 3840; idx += 128) {
    int j = idx >> 7, n = idx & 127;
    qs[j][n] = qb[idx]; ks[j][n] = kb2[idx]; vs[j][n] = vb2[idx];
  }
  for (int idx = tid; idx < 900; idx += 128) msk[idx / 30][idx % 30] = maskw[idx];
  __syncthreads();
  float p[30]; float iZ = 0.f; int hi = 0, ii = 0;
  if (tid < 120) {
    hi = tid / 30; ii = tid % 30;
    int hb = hi * 32;
    float4 qv[8];
#pragma unroll
    for (int dq = 0; dq < 8; dq++) qv[dq] = *(const float4*)&qs[ii][hb + dq * 4];
    float mx = -1e30f;
#pragma unroll
    for (int j = 0; j < 30; j++) {
      float s = 0.f;
      const float4* kr = (const float4*)&ks[j][hb];
#pragma unroll
      for (int dq = 0; dq < 8; dq++) {
        float4 kv = kr[dq];
        s += qv[dq].x * kv.x + qv[dq].y * kv.y + qv[dq].z * kv.z + qv[dq].w * kv.w;
      }
      s *= 0.17677669529663687f;
      p[j] = (msk[ii][j] != 0.f) ? s : -1e30f;
      mx = fmaxf(mx, p[j]);
    }
    float Z = 0.f;
#pragma unroll
    for (int j = 0; j < 30; j++) { float e = expf(p[j] - mx); p[j] = e; Z += e; }
    iZ = 1.0f / Z;
  }
  __syncthreads();
  if (tid < 120) {
    int hb = hi * 32;
#pragma unroll
    for (int dq = 0; dq < 8; dq++) {
      float sx = 0.f, sy = 0.f, sz = 0.f, sw2 = 0.f;
#pragma unroll
      for (int j = 0; j < 30; j++) {
        float4 vv = *(const float4*)&vs[j][hb + dq * 4];
        sx += p[j] * vv.x; sy += p[j] * vv.y; sz += p[j] * vv.z; sw2 += p[j] * vv.w;
      }
      float4 o = { sx * iZ, sy * iZ, sz * iZ, sw2 * iZ };
      *(float4*)&ogs[ii][hb + dq * 4] = o;
    }
  }
  __syncthreads();
  {
    int n = tid;
    float acc[30];
#pragma unroll
    for (int j = 0; j < 30; j++) acc[j] = 0.f;
    for (int d = 0; d < 128; d += 4) {
      float w0 = gWo[(d + 0) * 128 + n];
      float w1 = gWo[(d + 1) * 128 + n];
      float w2 = gWo[(d + 2) * 128 + n];
      float w3 = gWo[(d + 3) * 128 + n];
#pragma unroll
      for (int j = 0; j < 30; j++) {
        float4 og4 = *(const float4*)&ogs[j][d];
        acc[j] += og4.x * w0 + og4.y * w1 + og4.z * w2 + og4.w * w3;
      }
    }
    float gb = gbo[n];
    float* outp = out + ((long)(b * 128 + n) * 512 + t) * 30;
#pragma unroll
    for (int j = 0; j < 30; j++) outp[j] = acc[j] + gb;
  }
}

extern "C" void kernel_launch(void* const* d_in, const int* in_sizes, int n_in,
                              void* d_out, int out_size, void* d_ws, size_t ws_size,
                              hipStream_t stream) {
  fp x = (fp)d_in[0], Wq = (fp)d_in[1], Wk = (fp)d_in[2], Wv = (fp)d_in[3],
     Wo = (fp)d_in[4], bo = (fp)d_in[5], lw1 = (fp)d_in[6], lb1 = (fp)d_in[7],
     lw2 = (fp)d_in[8], lb2 = (fp)d_in[9],
     cw2 = (fp)d_in[10], cb2 = (fp)d_in[11], cw4 = (fp)d_in[12], cb4 = (fp)d_in[13],
     cw8 = (fp)d_in[14], cb8 = (fp)d_in[15], cw16 = (fp)d_in[16], cb16 = (fp)d_in[17],
     cw32 = (fp)d_in[18], cb32 = (fp)d_in[19], fw = (fp)d_in[20], be = (fp)d_in[21],
     gWq = (fp)d_in[22], gbq = (fp)d_in[23], gWk = (fp)d_in[24], gbk = (fp)d_in[25],
     gWv = (fp)d_in[26], gbv = (fp)d_in[27], gWo = (fp)d_in[28], gbo = (fp)d_in[29];
  (void)in_sizes; (void)n_in; (void)out_size; (void)ws_size;

  float* ws = (float*)d_ws;
  // ---- workspace map (float offsets), stage-ordered aliasing ----
  // stage1: qh 0..3.93M | ql 3.93M..7.86M | kh 7.86M..11.8M | kl 11.8M..15.7M
  //         vTh 15.7M..17.7M | vTl 17.7M..19.7M | rowstats 19.7M..20.15M | lam
  //         ob1 = 0.. | ob2 = 3.93M.. (over qh/ql)  | h1 23.6M..31.46M
  // stage2: ckh(u16) over 0..7.86M | ckl(u16) over 7.86M..15.7M | h2 15.7M..23.6M
  // stage3: qg 0..7.86M | kg 7.86M..15.7M | vg 23.6M..31.46M (over h1)
  // mask at 31.46M
  u16* qh  = (u16*)ws;
  u16* ql  = (u16*)(ws + 3932160L);
  u16* kh  = (u16*)(ws + 7864320L);
  u16* kl  = (u16*)(ws + 11796480L);
  u16* vTh = (u16*)(ws + 15728640L);
  u16* vTl = (u16*)(ws + 17694720L);
  float* rowstats = ws + 19660800L;
  float* lam      = ws + 20152320L;
  float* ob1 = ws;
  float* ob2 = ws + 3932160L;
  float* h1  = ws + 23592960L;
  u16* ckh = (u16*)ws;              // [30][32][128][128] bf16 hi
  u16* ckl = (u16*)(ws + 7864320L); // lo
  float* h2  = ws + 15728640L;
  float* qg  = ws;
  float* kg  = ws + 7864320L;
  float* vg  = ws + 23592960L;
  float* maskw = ws + 31457280L;

  k_adj<<<1, 64, 0, stream>>>(be, maskw);
  k_qkv<<<dim3(64, 4, 30), 128, 0, stream>>>(x, Wq, Wk, Wv, qh, ql, kh, kl, vTh, vTl);
  k_flash<<<dim3(32, 120), 256, 0, stream>>>(qh, ql, kh, kl, vTh, vTl, rowstats, ob1, ob2);
  k_lam<<<120, 64, 0, stream>>>(rowstats, lw1, lb1, lw2, lb2, lam);
  k_ep<<<dim3(64, 120), 128, 0, stream>>>(ob1, ob2, lam, Wo, bo, h1);
  k_ck<<<61440, 256, 0, stream>>>(fw, cw2, cw4, cw8, cw16, cw32, ckh, ckl);
  k_conv<<<dim3(8, 4, 30), 256, 0, stream>>>(h1, ckh, ckl, fw, cb2, cb4, cb8, cb16, cb32, h2);
  k_gqkv<<<3840, 128, 0, stream>>>(h2, gWq, gbq, gWk, gbk, gWv, gbv, qg, kg, vg);
  k_gattn<<<2048, 128, 0, stream>>>(qg, kg, vg, maskw, gWo, gbo, (float*)d_out);
}

// Round 5
// 882.130 us; speedup vs baseline: 3.2411x; 1.0961x over previous
//
#include <hip/hip_runtime.h>

// Problem constants: B=4, N=128, T=512, K=30 bands. All I/O fp32.
typedef const float* fp;
typedef unsigned short u16;
typedef __attribute__((ext_vector_type(8))) short bf16x8;   // 8 bf16 = 4 VGPRs
typedef __attribute__((ext_vector_type(4))) float f32x4;

__device__ __forceinline__ u16 f2b(float f) {
  union { float f; unsigned u; } a; a.f = f;
  unsigned u = a.u;
  u += 0x7fffu + ((u >> 16) & 1u);   // RNE
  return (u16)(u >> 16);
}
// split fp32 into hi (truncated bf16) + lo (RNE bf16 of exact remainder)
__device__ __forceinline__ void splitf(float x, u16& h, u16& l) {
  union { float f; unsigned u; } a; a.f = x;
  unsigned hu = a.u & 0xFFFF0000u;
  h = (u16)(hu >> 16);
  union { unsigned u; float f; } b; b.u = hu;
  l = f2b(x - b.f);
}

// ---------------- Stage 0: adjacency mask ----------------
__global__ __launch_bounds__(64) void k_adj(fp be, float* mask) {
  __shared__ float e[30][65];
  __shared__ float sim[30][33];
  __shared__ float A[30][33];
  int tid = threadIdx.x;
  for (int idx = tid; idx < 30 * 64; idx += 64) e[idx / 64][idx % 64] = be[idx];
  __syncthreads();
  if (tid < 30) {
    float s = 0.f;
    for (int d = 0; d < 64; d++) s += e[tid][d] * e[tid][d];
    float sc = 1.0f / (sqrtf(s) + 1e-8f);
    for (int d = 0; d < 64; d++) e[tid][d] *= sc;
  }
  __syncthreads();
  if (tid < 30) {
    for (int j = 0; j < 30; j++) {
      float s = 0.f;
      for (int d = 0; d < 64; d++) s += e[tid][d] * e[j][d];
      sim[tid][j] = s;
    }
    for (int j = 0; j < 30; j++) A[tid][j] = 0.f;
  }
  __syncthreads();
  if (tid < 30) {
    unsigned used = 0;
    for (int t = 0; t < 5; t++) {
      float best = -1e30f; int bi = 0;
      for (int j = 0; j < 30; j++)
        if (!((used >> j) & 1u) && sim[tid][j] > best) { best = sim[tid][j]; bi = j; }
      A[tid][bi] = best; used |= 1u << bi;
    }
  }
  __syncthreads();
  for (int idx = tid; idx < 900; idx += 64) {
    int i = idx / 30, j = idx % 30;
    float s = A[i][j] + A[j][i];
    mask[idx] = (s != 0.0f) ? 1.0f : 0.0f;
  }
}

// ---------------- Prep: transpose+split band weights into B-frag layout -------
// wqkT[kb][m 0..319][n 0..127]  (m: q 0..127, k 128..255, v 256..319)
__global__ __launch_bounds__(256) void k_wt_band(fp Wq, fp Wk, fp Wv, u16* wh, u16* wl) {
  int kb = blockIdx.x, which = blockIdx.y;
  __shared__ float wsb[128][129];
  int tid = threadIdx.x;
  int M = (which == 2) ? 64 : 128;
  int sh = (which == 2) ? 6 : 7;
  fp src = (which == 0) ? (Wq + kb * 16384) : (which == 1) ? (Wk + kb * 16384) : (Wv + kb * 8192);
  for (int i = tid; i < 128 * M; i += 256) {
    int n = i >> sh, m = i & (M - 1);
    wsb[n][m] = src[i];
  }
  __syncthreads();
  long base = (long)kb * 40960 + which * 16384;
  for (int o = tid; o < 128 * M; o += 256) {
    int m = o >> 7, n = o & 127;
    u16 h, l; splitf(wsb[n][m], h, l);
    wh[base + m * 128 + n] = h; wl[base + m * 128 + n] = l;
  }
}

// gwT[m 0..511][n]: gWq 0..127, gWk 128..255, gWv 256..383, gWo 384..511
__global__ __launch_bounds__(256) void k_wt_graph(fp gWq, fp gWk, fp gWv, fp gWo,
                                                  u16* wh, u16* wl) {
  int w = blockIdx.x;
  fp src = (w == 0) ? gWq : (w == 1) ? gWk : (w == 2) ? gWv : gWo;
  __shared__ float wsb[128][129];
  int tid = threadIdx.x;
  for (int i = tid; i < 16384; i += 256) wsb[i >> 7][i & 127] = src[i];
  __syncthreads();
  long base = (long)w * 16384;
  for (int o = tid; o < 16384; o += 256) {
    int m = o >> 7, n = o & 127;
    u16 h, l; splitf(wsb[n][m], h, l);
    wh[base + m * 128 + n] = h; wl[base + m * 128 + n] = l;
  }
}

// ---------------- Stage 1a: QKV projections via MFMA ----------------
// out: qh/ql,kh/kl [pair][t][128] bf16; vTh/vTl [pair][64][512]
__global__ __launch_bounds__(256) void k_qkv(fp x, const u16* wh, const u16* wl,
                                             u16* qh, u16* ql, u16* kh, u16* kl,
                                             u16* vTh, u16* vTl) {
  int kb = blockIdx.z, b = blockIdx.y, t0 = blockIdx.x * 64;
  int tid = threadIdx.x;
  int wave = tid >> 6, lane = tid & 63, l15 = lane & 15, quad = lane >> 4;
  __shared__ u16 xs_h[64 * 136];
  __shared__ u16 xs_l[64 * 136];
  for (int i = tid; i < 8192; i += 256) {
    int tl = i >> 7, n = i & 127;
    float v = x[((long)(b * 128 + n) * 512 + t0 + tl) * 30 + kb];
    u16 h, l; splitf(v, h, l);
    xs_h[tl * 136 + n] = h; xs_l[tl * 136 + n] = l;
  }
  __syncthreads();
  int arow = wave * 16 + l15;
  bf16x8 Ah[4], Al[4];
#pragma unroll
  for (int kc = 0; kc < 4; kc++) {
    Ah[kc] = *(const bf16x8*)(xs_h + arow * 136 + kc * 32 + quad * 8);
    Al[kc] = *(const bf16x8*)(xs_l + arow * 136 + kc * 32 + quad * 8);
  }
  int pair = kb * 4 + b;
  const u16* wbh = wh + (long)kb * 40960;
  const u16* wbl = wl + (long)kb * 40960;
  for (int c = 0; c < 20; c++) {
    f32x4 d = {0.f, 0.f, 0.f, 0.f};
#pragma unroll
    for (int kc = 0; kc < 4; kc++) {
      long boff = (long)(c * 16 + l15) * 128 + kc * 32 + quad * 8;
      bf16x8 Bh = *(const bf16x8*)(wbh + boff);
      bf16x8 Bl = *(const bf16x8*)(wbl + boff);
      d = __builtin_amdgcn_mfma_f32_16x16x32_bf16(Ah[kc], Bh, d, 0, 0, 0);
      d = __builtin_amdgcn_mfma_f32_16x16x32_bf16(Ah[kc], Bl, d, 0, 0, 0);
      d = __builtin_amdgcn_mfma_f32_16x16x32_bf16(Al[kc], Bh, d, 0, 0, 0);
    }
    if (c < 8) {
      int m = c * 16 + l15;
#pragma unroll
      for (int r = 0; r < 4; r++) {
        int trow = t0 + wave * 16 + quad * 4 + r;
        u16 h, l; splitf(d[r], h, l);
        long o = ((long)pair * 512 + trow) * 128 + m;
        qh[o] = h; ql[o] = l;
      }
    } else if (c < 16) {
      int m = (c - 8) * 16 + l15;
#pragma unroll
      for (int r = 0; r < 4; r++) {
        int trow = t0 + wave * 16 + quad * 4 + r;
        u16 h, l; splitf(d[r], h, l);
        long o = ((long)pair * 512 + trow) * 128 + m;
        kh[o] = h; kl[o] = l;
      }
    } else {
      int dcol = (c - 16) * 16 + l15;
#pragma unroll
      for (int r = 0; r < 4; r++) {
        int trow = t0 + wave * 16 + quad * 4 + r;
        u16 h, l; splitf(d[r], h, l);
        long o = ((long)pair * 64 + dcol) * 512 + trow;
        vTh[o] = h; vTl[o] = l;
      }
    }
  }
}

// ---------------- Stage 1b: fused flash kernel ----------------
__global__ __launch_bounds__(256) void k_flash(const u16* qh, const u16* ql,
                                               const u16* kh, const u16* kl,
                                               const u16* vTh, const u16* vTl,
                                               float* rowstats, float* ob1, float* ob2) {
  int pair = blockIdx.y;
  int t0 = blockIdx.x * 16;
  int tid = threadIdx.x;
  int wave = tid >> 6, lane = tid & 63;
  int l15 = lane & 15, quad = lane >> 4;

  __shared__ float fbig[8704];
  __shared__ float st[2][16][4][4];
  __shared__ float fin[2][16][2];

  const long pb = (long)pair * 512 * 128;
  const u16* qhb = qh + pb; const u16* qlb = ql + pb;
  const u16* khb = kh + pb; const u16* klb = kl + pb;

  float sc[2][8][4];
  float mw[2][4];
#pragma unroll
  for (int h = 0; h < 2; h++) {
    long abase = (long)(t0 + l15) * 128 + h * 64 + quad * 8;
    bf16x8 Ah0 = *(const bf16x8*)(qhb + abase);
    bf16x8 Ah1 = *(const bf16x8*)(qhb + abase + 32);
    bf16x8 Al0 = *(const bf16x8*)(qlb + abase);
    bf16x8 Al1 = *(const bf16x8*)(qlb + abase + 32);
#pragma unroll
    for (int ct = 0; ct < 8; ct++) {
      int scol = wave * 128 + ct * 16 + l15;
      long bbase = (long)scol * 128 + h * 64 + quad * 8;
      bf16x8 Bh0 = *(const bf16x8*)(khb + bbase);
      bf16x8 Bh1 = *(const bf16x8*)(khb + bbase + 32);
      bf16x8 Bl0 = *(const bf16x8*)(klb + bbase);
      bf16x8 Bl1 = *(const bf16x8*)(klb + bbase + 32);
      f32x4 d = {0.f, 0.f, 0.f, 0.f};
      d = __builtin_amdgcn_mfma_f32_16x16x32_bf16(Ah0, Bh0, d, 0, 0, 0);
      d = __builtin_amdgcn_mfma_f32_16x16x32_bf16(Ah1, Bh1, d, 0, 0, 0);
      d = __builtin_amdgcn_mfma_f32_16x16x32_bf16(Ah0, Bl0, d, 0, 0, 0);
      d = __builtin_amdgcn_mfma_f32_16x16x32_bf16(Ah1, Bl1, d, 0, 0, 0);
      d = __builtin_amdgcn_mfma_f32_16x16x32_bf16(Al0, Bh0, d, 0, 0, 0);
      d = __builtin_amdgcn_mfma_f32_16x16x32_bf16(Al1, Bh1, d, 0, 0, 0);
#pragma unroll
      for (int r = 0; r < 4; r++) sc[h][ct][r] = d[r] * 0.25f;
    }
  }
#pragma unroll
  for (int h = 0; h < 2; h++)
#pragma unroll
    for (int r = 0; r < 4; r++) {
      float m = -1e30f, mnv = 1e30f;
#pragma unroll
      for (int ct = 0; ct < 8; ct++) { m = fmaxf(m, sc[h][ct][r]); mnv = fminf(mnv, sc[h][ct][r]); }
      for (int d = 1; d < 16; d <<= 1) { m = fmaxf(m, __shfl_xor(m, d)); mnv = fminf(mnv, __shfl_xor(mnv, d)); }
      float z = 0.f, s2 = 0.f;
#pragma unroll
      for (int ct = 0; ct < 8; ct++) {
        float e = expf(sc[h][ct][r] - m); z += e; s2 += e * e;
        sc[h][ct][r] = e;                       // keep e for the p-phase
      }
      for (int d = 1; d < 16; d <<= 1) { z += __shfl_xor(z, d); s2 += __shfl_xor(s2, d); }
      mw[h][r] = m;
      if (l15 == 0) {
        st[h][quad * 4 + r][wave][0] = m;  st[h][quad * 4 + r][wave][1] = z;
        st[h][quad * 4 + r][wave][2] = s2; st[h][quad * 4 + r][wave][3] = mnv;
      }
    }
  __syncthreads();
  if (tid < 32) {
    int row = tid & 15, h = tid >> 4;
    float Mf = -1e30f, mnf = 1e30f;
    for (int w = 0; w < 4; w++) { Mf = fmaxf(Mf, st[h][row][w][0]); mnf = fminf(mnf, st[h][row][w][3]); }
    float Z = 0.f, S2 = 0.f;
    for (int w = 0; w < 4; w++) {
      float f = expf(st[h][row][w][0] - Mf);
      Z += st[h][row][w][1] * f; S2 += st[h][row][w][2] * f * f;
    }
    float* o = rowstats + ((long)pair * 512 + t0 + row) * 8 + h * 4;
    o[0] = Mf; o[1] = Z; o[2] = S2; o[3] = mnf;
    fin[h][row][0] = Mf; fin[h][row][1] = 1.0f / Z;
  }
  __syncthreads();
  u16* pbuf = (u16*)fbig;   // [h][wave][row16][136]
#pragma unroll
  for (int h = 0; h < 2; h++)
#pragma unroll
    for (int r = 0; r < 4; r++) {
      int row = quad * 4 + r;
      float scale = expf(mw[h][r] - fin[h][row][0]) * fin[h][row][1];
#pragma unroll
      for (int ct = 0; ct < 8; ct++) {
        float p = sc[h][ct][r] * scale;
        pbuf[((h * 4 + wave) * 16 + row) * 136 + ct * 16 + l15] = f2b(p);
      }
    }
  __syncthreads();
  f32x4 acc[2][4];
#pragma unroll
  for (int h = 0; h < 2; h++)
#pragma unroll
    for (int nt = 0; nt < 4; nt++) acc[h][nt] = {0.f, 0.f, 0.f, 0.f};
  const u16* vThb = vTh + (long)pair * 64 * 512;
  const u16* vTlb = vTl + (long)pair * 64 * 512;
#pragma unroll
  for (int kc = 0; kc < 4; kc++) {
    int sbase = wave * 128 + kc * 32 + quad * 8;
    bf16x8 A0 = *(const bf16x8*)(pbuf + ((0 * 4 + wave) * 16 + l15) * 136 + kc * 32 + quad * 8);
    bf16x8 A1 = *(const bf16x8*)(pbuf + ((1 * 4 + wave) * 16 + l15) * 136 + kc * 32 + quad * 8);
#pragma unroll
    for (int nt = 0; nt < 4; nt++) {
      long vo = (long)(nt * 16 + l15) * 512 + sbase;
      bf16x8 Vh = *(const bf16x8*)(vThb + vo);
      bf16x8 Vl = *(const bf16x8*)(vTlb + vo);
      acc[0][nt] = __builtin_amdgcn_mfma_f32_16x16x32_bf16(A0, Vh, acc[0][nt], 0, 0, 0);
      acc[0][nt] = __builtin_amdgcn_mfma_f32_16x16x32_bf16(A0, Vl, acc[0][nt], 0, 0, 0);
      acc[1][nt] = __builtin_amdgcn_mfma_f32_16x16x32_bf16(A1, Vh, acc[1][nt], 0, 0, 0);
      acc[1][nt] = __builtin_amdgcn_mfma_f32_16x16x32_bf16(A1, Vl, acc[1][nt], 0, 0, 0);
    }
  }
  __syncthreads();
  float* obr = fbig; // [wave][h][row16][68]
#pragma unroll
  for (int h = 0; h < 2; h++)
#pragma unroll
    for (int nt = 0; nt < 4; nt++)
#pragma unroll
      for (int r = 0; r < 4; r++)
        obr[((wave * 2 + h) * 16 + quad * 4 + r) * 68 + nt * 16 + l15] = acc[h][nt][r];
  __syncthreads();
  for (int i = tid; i < 2048; i += 256) {
    int h = i >> 10, row = (i >> 6) & 15, d = i & 63;
    float s = 0.f;
    for (int w = 0; w < 4; w++) s += obr[((w * 2 + h) * 16 + row) * 68 + d];
    float* dst = (h == 0 ? ob1 : ob2);
    dst[((long)pair * 512 + t0 + row) * 64 + d] = s;
  }
}

// ---------------- Stage 1c: lambda MLP ----------------
__global__ __launch_bounds__(64) void k_lam(const float* rowstats, fp lw1, fp lb1,
                                            fp lw2, fp lb2, float* lam) {
  int pair = blockIdx.x; int kb = pair >> 2;
  int tid = threadIdx.x;
  const float* rs = rowstats + (long)pair * 512 * 8;
  float mx1 = -1e30f, mn1 = 1e30f, ss1 = 0.f, mx2 = -1e30f, mn2 = 1e30f, ss2 = 0.f;
  for (int j = 0; j < 8; j++) {
    const float* rr = rs + (long)(j * 64 + tid) * 8;
    float M1 = rr[0], Z1 = rr[1], S21 = rr[2], m1 = rr[3];
    float M2 = rr[4], Z2 = rr[5], S22 = rr[6], m2 = rr[7];
    mx1 = fmaxf(mx1, 1.0f / Z1); mn1 = fminf(mn1, expf(m1 - M1) / Z1); ss1 += S21 / (Z1 * Z1);
    mx2 = fmaxf(mx2, 1.0f / Z2); mn2 = fminf(mn2, expf(m2 - M2) / Z2); ss2 += S22 / (Z2 * Z2);
  }
  __shared__ float red[64][8];
  red[tid][0] = mx1; red[tid][1] = mn1; red[tid][2] = ss1;
  red[tid][3] = mx2; red[tid][4] = mn2; red[tid][5] = ss2;
  __syncthreads();
  if (tid == 0) {
    for (int e = 1; e < 64; e++) {
      mx1 = fmaxf(mx1, red[e][0]); mn1 = fminf(mn1, red[e][1]); ss1 += red[e][2];
      mx2 = fmaxf(mx2, red[e][3]); mn2 = fminf(mn2, red[e][4]); ss2 += red[e][5];
    }
    const float mean = 1.0f / 512.0f;
    const float n = 262144.0f;
    float v1 = (ss1 - n * mean * mean) / (n - 1.0f); float sd1 = sqrtf(fmaxf(v1, 0.f));
    float v2 = (ss2 - n * mean * mean) / (n - 1.0f); float sd2 = sqrtf(fmaxf(v2, 0.f));
    float stv[8] = { mean, sd1, mx1, mn1, mean, sd2, mx2, mn2 };
    float acc = lb2[kb];
    for (int o = 0; o < 16; o++) {
      float h = lb1[kb * 16 + o];
      for (int i = 0; i < 8; i++) h += stv[i] * lw1[(kb * 8 + i) * 16 + o];
      h = fmaxf(h, 0.f);
      acc += h * lw2[kb * 16 + o];
    }
    lam[pair] = 1.0f / (1.0f + expf(-acc));
  }
}

// ---------------- Stage 1d: epilogue h1 = (ob1 - lam*ob2)@Wo + bo -------------
__global__ __launch_bounds__(128) void k_ep(const float* ob1, const float* ob2,
                                            const float* lam, fp Wo, fp bo, float* h1) {
  int pair = blockIdx.y; int kb = pair >> 2, b = pair & 3;
  int t0 = blockIdx.x * 8;
  int tid = threadIdx.x;
  float lv = lam[pair];
  __shared__ float obs[8][68];
  for (int i = tid; i < 512; i += 128) {
    int r = i >> 6, d = i & 63;
    long o = ((long)pair * 512 + t0 + r) * 64 + d;
    obs[r][d] = ob1[o] - lv * ob2[o];
  }
  __syncthreads();
  int n = tid;
  float acc[8];
#pragma unroll
  for (int r = 0; r < 8; r++) acc[r] = bo[kb * 128 + n];
  for (int dd = 0; dd < 64; dd++) {
    float w = Wo[(kb * 64 + dd) * 128 + n];
#pragma unroll
    for (int r = 0; r < 8; r++) acc[r] += obs[r][dd] * w;
  }
#pragma unroll
  for (int r = 0; r < 8; r++)
    h1[((long)(b * 30 + kb) * 512 + t0 + r) * 128 + n] = acc[r];
}

// ---------------- Stage 2a: combined conv kernel, packed active taps ----------
// layout [g 0..455][no 128][ni 128]; g = packed (kb, tap)
__global__ __launch_bounds__(256) void k_ck(fp fw, fp cw2, fp cw4, fp cw8,
                                            fp cw16, fp cw32, u16* ckh, u16* ckl) {
  long idx = (long)blockIdx.x * 256 + threadIdx.x;
  int ni = idx & 127;
  int no = (idx >> 7) & 127;
  int g  = (int)(idx >> 14);
  int kb, r;
  if (g < 192)      { kb = g >> 5;                r = g & 31; }
  else if (g < 336) { int gg = g - 192; kb = 6 + (gg >> 4);  r = 8 + (gg & 15); }
  else              { int gg = g - 336; kb = 15 + (gg >> 3); r = 12 + (gg & 7); }
  float f0 = fw[kb * 3 + 0], f1 = fw[kb * 3 + 1], f2 = fw[kb * 3 + 2];
  float mx = fmaxf(f0, fmaxf(f1, f2));
  float e0 = expf(f0 - mx), e1 = expf(f1 - mx), e2 = expf(f2 - mx);
  float zi = 1.0f / (e0 + e1 + e2);
  float sw[3] = { e0 * zi, e1 * zi, e2 * zi };
  int sbase; fp cws[3];
  if (kb < 6)       { sbase = 8; cws[0] = cw8;  cws[1] = cw16; cws[2] = cw32; }
  else if (kb < 15) { sbase = 4; cws[0] = cw4;  cws[1] = cw8;  cws[2] = cw16; }
  else              { sbase = 2; cws[0] = cw2;  cws[1] = cw4;  cws[2] = cw8;  }
  float val = 0.f;
  int rs = r - 16;
#pragma unroll
  for (int j = 0; j < 3; j++) {
    int s = sbase << j;
    int tau = rs + (s >> 1);
    if (tau >= 0 && tau < s) val += sw[j] * cws[j][((long)no * 128 + ni) * s + tau];
  }
  u16 h, l; splitf(val, h, l);
  ckh[idx] = h; ckl[idx] = l;
}

// ---------------- Stage 2b: per-band conv via MFMA; emits split-bf16 h2 -------
__global__ __launch_bounds__(256) void k_conv(const float* h1, const u16* ckh,
                                              const u16* ckl, fp fw,
                                              fp cb2, fp cb4, fp cb8, fp cb16,
                                              fp cb32, u16* h2h, u16* h2l) {
  int kb = blockIdx.z, b = blockIdx.y, t0 = blockIdx.x * 64;
  int tid = threadIdx.x;
  int wave = tid >> 6, lane = tid & 63, l15 = lane & 15, quad = lane >> 4;
  __shared__ u16 xs_h[96 * 136];
  __shared__ u16 xs_l[96 * 136];
  const float* xrow = h1 + (long)(b * 30 + kb) * 512 * 128;
  for (int i = tid; i < 3072; i += 256) {
    int row = i >> 5, c4 = (i & 31) << 2;
    int t = t0 - 16 + row;
    float4 xv = {0.f, 0.f, 0.f, 0.f};
    if (t >= 0 && t < 512) xv = *(const float4*)(xrow + (long)t * 128 + c4);
    u16 h, l;
    splitf(xv.x, h, l); xs_h[row * 136 + c4 + 0] = h; xs_l[row * 136 + c4 + 0] = l;
    splitf(xv.y, h, l); xs_h[row * 136 + c4 + 1] = h; xs_l[row * 136 + c4 + 1] = l;
    splitf(xv.z, h, l); xs_h[row * 136 + c4 + 2] = h; xs_l[row * 136 + c4 + 2] = l;
    splitf(xv.w, h, l); xs_h[row * 136 + c4 + 3] = h; xs_l[row * 136 + c4 + 3] = l;
  }
  float f0 = fw[kb * 3 + 0], f1 = fw[kb * 3 + 1], f2 = fw[kb * 3 + 2];
  float mx = fmaxf(f0, fmaxf(f1, f2));
  float e0 = expf(f0 - mx), e1 = expf(f1 - mx), e2 = expf(f2 - mx);
  float zi = 1.0f / (e0 + e1 + e2);
  float sw0 = e0 * zi, sw1 = e1 * zi, sw2 = e2 * zi;
  int rlo, rhi, gbase; fp c0, c1, c2;
  if (kb < 6)       { rlo = 0;  rhi = 32; gbase = kb * 32;            c0 = cb8; c1 = cb16; c2 = cb32; }
  else if (kb < 15) { rlo = 8;  rhi = 24; gbase = 192 + (kb - 6) * 16;  c0 = cb4; c1 = cb8;  c2 = cb16; }
  else              { rlo = 12; rhi = 20; gbase = 336 + (kb - 15) * 8;  c0 = cb2; c1 = cb4;  c2 = cb8;  }
  __syncthreads();
  f32x4 acc[4][2];
#pragma unroll
  for (int mt = 0; mt < 4; mt++) { acc[mt][0] = {0.f,0.f,0.f,0.f}; acc[mt][1] = {0.f,0.f,0.f,0.f}; }
  for (int r = rlo; r < rhi; r++) {
    const u16* wh = ckh + ((long)(gbase + r - rlo) * 128 + wave * 32 + l15) * 128;
    const u16* wl = ckl + ((long)(gbase + r - rlo) * 128 + wave * 32 + l15) * 128;
#pragma unroll
    for (int c = 0; c < 4; c++) {
      int koff = c * 32 + quad * 8;
      bf16x8 Bh0 = *(const bf16x8*)(wh + koff);
      bf16x8 Bh1 = *(const bf16x8*)(wh + 2048 + koff);
      bf16x8 Bl0 = *(const bf16x8*)(wl + koff);
      bf16x8 Bl1 = *(const bf16x8*)(wl + 2048 + koff);
#pragma unroll
      for (int mt = 0; mt < 4; mt++) {
        int arow = mt * 16 + l15 + r;
        bf16x8 Ah = *(const bf16x8*)(xs_h + arow * 136 + koff);
        bf16x8 Al = *(const bf16x8*)(xs_l + arow * 136 + koff);
        acc[mt][0] = __builtin_amdgcn_mfma_f32_16x16x32_bf16(Ah, Bh0, acc[mt][0], 0, 0, 0);
        acc[mt][0] = __builtin_amdgcn_mfma_f32_16x16x32_bf16(Ah, Bl0, acc[mt][0], 0, 0, 0);
        acc[mt][0] = __builtin_amdgcn_mfma_f32_16x16x32_bf16(Al, Bh0, acc[mt][0], 0, 0, 0);
        acc[mt][1] = __builtin_amdgcn_mfma_f32_16x16x32_bf16(Ah, Bh1, acc[mt][1], 0, 0, 0);
        acc[mt][1] = __builtin_amdgcn_mfma_f32_16x16x32_bf16(Ah, Bl1, acc[mt][1], 0, 0, 0);
        acc[mt][1] = __builtin_amdgcn_mfma_f32_16x16x32_bf16(Al, Bh1, acc[mt][1], 0, 0, 0);
      }
    }
  }
  int no0 = wave * 32 + l15;
  float bias0 = sw0 * c0[no0] + sw1 * c1[no0] + sw2 * c2[no0];
  float bias1 = sw0 * c0[no0 + 16] + sw1 * c1[no0 + 16] + sw2 * c2[no0 + 16];
#pragma unroll
  for (int mt = 0; mt < 4; mt++)
#pragma unroll
    for (int reg = 0; reg < 4; reg++) {
      int t = t0 + mt * 16 + quad * 4 + reg;
      long ob = ((long)(b * 512 + t) * 30 + kb) * 128 + no0;
      u16 h, l;
      splitf(acc[mt][0][reg] + bias0, h, l); h2h[ob] = h;      h2l[ob] = l;
      splitf(acc[mt][1][reg] + bias1, h, l); h2h[ob + 16] = h; h2l[ob + 16] = l;
    }
}

// ---------------- Stage 3: fused graph QKV + attention + out GEMM -------------
// one block per (b,t); h2 rows (b,t,kb 0..29) are contiguous.
__global__ __launch_bounds__(256) void k_gattn(const u16* h2h, const u16* h2l,
                                               const u16* gwh, const u16* gwl,
                                               const float* maskw,
                                               fp gbq, fp gbk, fp gbv, fp gbo,
                                               float* out) {
  int m = blockIdx.x; int b = m >> 9; int t = m & 511;
  int tid = threadIdx.x;
  int wave = tid >> 6, lane = tid & 63, l15 = lane & 15, quad = lane >> 4;
  __shared__ float qs[32][136];
  __shared__ float ks[32][136];
  __shared__ float vs[32][136];
  u16* ogs_h = (u16*)&qs[0][0];
  u16* ogs_l = ogs_h + 32 * 136;

  // ---- Phase 1: QKV projection via MFMA ----
  {
    int mtile = wave & 1;
    int c0 = (wave >> 1) * 12;
    long abase0 = (long)m * 30 * 128;
    bf16x8 Ah[4], Al[4];
    bf16x8 zero8 = {0, 0, 0, 0, 0, 0, 0, 0};
    int row = mtile * 16 + l15;
#pragma unroll
    for (int kc = 0; kc < 4; kc++) {
      if (row < 30) {
        Ah[kc] = *(const bf16x8*)(h2h + abase0 + (long)row * 128 + kc * 32 + quad * 8);
        Al[kc] = *(const bf16x8*)(h2l + abase0 + (long)row * 128 + kc * 32 + quad * 8);
      } else { Ah[kc] = zero8; Al[kc] = zero8; }
    }
    for (int cc = 0; cc < 12; cc++) {
      int c = c0 + cc;
      f32x4 d = {0.f, 0.f, 0.f, 0.f};
#pragma unroll
      for (int kc = 0; kc < 4; kc++) {
        long boff = (long)(c * 16 + l15) * 128 + kc * 32 + quad * 8;
        bf16x8 Bh = *(const bf16x8*)(gwh + boff);
        bf16x8 Bl = *(const bf16x8*)(gwl + boff);
        d = __builtin_amdgcn_mfma_f32_16x16x32_bf16(Ah[kc], Bh, d, 0, 0, 0);
        d = __builtin_amdgcn_mfma_f32_16x16x32_bf16(Ah[kc], Bl, d, 0, 0, 0);
        d = __builtin_amdgcn_mfma_f32_16x16x32_bf16(Al[kc], Bh, d, 0, 0, 0);
      }
      int region = c >> 3;
      int ch = (c & 7) * 16 + l15;
      float bias = (region == 0) ? gbq[ch] : (region == 1) ? gbk[ch] : gbv[ch];
      float (*dst)[136] = (region == 0) ? qs : (region == 1) ? ks : vs;
#pragma unroll
      for (int r = 0; r < 4; r++) {
        int rowo = mtile * 16 + quad * 4 + r;
        if (rowo < 30) dst[rowo][ch] = d[r] + bias;
      }
    }
  }
  __syncthreads();

  // ---- Phase 2: 30x30 4-head attention (VALU) ----
  float p[30]; float iZ = 0.f; int hi = 0, ii = 0;
  if (tid < 120) {
    hi = tid / 30; ii = tid % 30;
    int hb = hi * 32;
    float4 qv[8];
#pragma unroll
    for (int dq = 0; dq < 8; dq++) qv[dq] = *(const float4*)&qs[ii][hb + dq * 4];
    float mx = -1e30f;
#pragma unroll
    for (int j = 0; j < 30; j++) {
      float s = 0.f;
      const float4* kr = (const float4*)&ks[j][hb];
#pragma unroll
      for (int dq = 0; dq < 8; dq++) {
        float4 kv = kr[dq];
        s += qv[dq].x * kv.x + qv[dq].y * kv.y + qv[dq].z * kv.z + qv[dq].w * kv.w;
      }
      s *= 0.17677669529663687f;
      p[j] = (maskw[ii * 30 + j] != 0.f) ? s : -1e30f;
      mx = fmaxf(mx, p[j]);
    }
    float Z = 0.f;
#pragma unroll
    for (int j = 0; j < 30; j++) { float e = expf(p[j] - mx); p[j] = e; Z += e; }
    iZ = 1.0f / Z;
  }
  __syncthreads();   // everyone done reading qs
  if (tid < 120) {
    int hb = hi * 32;
#pragma unroll
    for (int dq = 0; dq < 8; dq++) {
      float sx = 0.f, sy = 0.f, sz = 0.f, sw2 = 0.f;
#pragma unroll
      for (int j = 0; j < 30; j++) {
        float4 vv = *(const float4*)&vs[j][hb + dq * 4];
        sx += p[j] * vv.x; sy += p[j] * vv.y; sz += p[j] * vv.z; sw2 += p[j] * vv.w;
      }
      float o4[4] = { sx * iZ, sy * iZ, sz * iZ, sw2 * iZ };
#pragma unroll
      for (int cpt = 0; cpt < 4; cpt++) {
        u16 h, l; splitf(o4[cpt], h, l);
        ogs_h[ii * 136 + hb + dq * 4 + cpt] = h;
        ogs_l[ii * 136 + hb + dq * 4 + cpt] = l;
      }
    }
  }
  __syncthreads();

  // ---- Phase 3: out = og @ gWo + gbo via MFMA ----
  {
    int mtile = wave & 1;
    int nc0 = (wave >> 1) * 4;
    int row = mtile * 16 + l15;
    bf16x8 Ah[4], Al[4];
#pragma unroll
    for (int kc = 0; kc < 4; kc++) {
      Ah[kc] = *(const bf16x8*)(ogs_h + row * 136 + kc * 32 + quad * 8);
      Al[kc] = *(const bf16x8*)(ogs_l + row * 136 + kc * 32 + quad * 8);
    }
    for (int cc = 0; cc < 4; cc++) {
      int nchunk = nc0 + cc;
      f32x4 d = {0.f, 0.f, 0.f, 0.f};
#pragma unroll
      for (int kc = 0; kc < 4; kc++) {
        long boff = (long)(384 + nchunk * 16 + l15) * 128 + kc * 32 + quad * 8;
        bf16x8 Bh = *(const bf16x8*)(gwh + boff);
        bf16x8 Bl = *(const bf16x8*)(gwl + boff);
        d = __builtin_amdgcn_mfma_f32_16x16x32_bf16(Ah[kc], Bh, d, 0, 0, 0);
        d = __builtin_amdgcn_mfma_f32_16x16x32_bf16(Ah[kc], Bl, d, 0, 0, 0);
        d = __builtin_amdgcn_mfma_f32_16x16x32_bf16(Al[kc], Bh, d, 0, 0, 0);
      }
      int n = nchunk * 16 + l15;
      float gb = gbo[n];
      long obase = ((long)(b * 128 + n) * 512 + t) * 30;
#pragma unroll
      for (int r = 0; r < 4; r++) {
        int kbo = mtile * 16 + quad * 4 + r;
        if (kbo < 30) out[obase + kbo] = d[r] + gb;
      }
    }
  }
}

extern "C" void kernel_launch(void* const* d_in, const int* in_sizes, int n_in,
                              void* d_out, int out_size, void* d_ws, size_t ws_size,
                              hipStream_t stream) {
  fp x = (fp)d_in[0], Wq = (fp)d_in[1], Wk = (fp)d_in[2], Wv = (fp)d_in[3],
     Wo = (fp)d_in[4], bo = (fp)d_in[5], lw1 = (fp)d_in[6], lb1 = (fp)d_in[7],
     lw2 = (fp)d_in[8], lb2 = (fp)d_in[9],
     cw2 = (fp)d_in[10], cb2 = (fp)d_in[11], cw4 = (fp)d_in[12], cb4 = (fp)d_in[13],
     cw8 = (fp)d_in[14], cb8 = (fp)d_in[15], cw16 = (fp)d_in[16], cb16 = (fp)d_in[17],
     cw32 = (fp)d_in[18], cb32 = (fp)d_in[19], fw = (fp)d_in[20], be = (fp)d_in[21],
     gWq = (fp)d_in[22], gbq = (fp)d_in[23], gWk = (fp)d_in[24], gbk = (fp)d_in[25],
     gWv = (fp)d_in[26], gbv = (fp)d_in[27], gWo = (fp)d_in[28], gbo = (fp)d_in[29];
  (void)in_sizes; (void)n_in; (void)out_size; (void)ws_size;

  float* ws = (float*)d_ws;
  // ---- workspace map (float offsets), race-free stage-ordered aliasing ----
  u16* qh  = (u16*)ws;                          // [120][512][128]
  u16* ql  = (u16*)(ws + 3932160L);
  u16* kh  = (u16*)(ws + 7864320L);
  u16* kl  = (u16*)(ws + 11796480L);
  u16* vTh = (u16*)(ws + 15728640L);            // [120][64][512]
  u16* vTl = (u16*)(ws + 17694720L);
  float* rowstats = ws + 19660800L;             // [120][512][8]
  float* lam      = ws + 20152320L;             // [120]
  u16* wqkT_h = (u16*)(ws + 20152448L);         // [30][320][128]
  u16* wqkT_l = (u16*)(ws + 20766848L);
  u16* gwT_h  = (u16*)(ws + 21381248L);         // [512][128]
  u16* gwT_l  = (u16*)(ws + 21414016L);
  float* maskw = ws + 21446784L;                // [900]
  float* ob1 = ws + 21447808L;                  // [120][512][64]
  float* ob2 = ws + 25379968L;
  float* h1  = ws;                              // over dead qh/ql (after k_flash)
  u16* h2h = (u16*)(ws + 7864320L);             // over dead kh/kl (after k_flash)
  u16* h2l = (u16*)(ws + 11796480L);
  u16* ckh = (u16*)(ws + 21447808L);            // over dead ob1/ob2 (after k_ep)
  u16* ckl = (u16*)(ws + 25183360L);
  // peak usage: 29,312,128 floats = 117.2 MB

  k_adj<<<1, 64, 0, stream>>>(be, maskw);
  k_wt_band<<<dim3(30, 3), 256, 0, stream>>>(Wq, Wk, Wv, wqkT_h, wqkT_l);
  k_wt_graph<<<4, 256, 0, stream>>>(gWq, gWk, gWv, gWo, gwT_h, gwT_l);
  k_qkv<<<dim3(8, 4, 30), 256, 0, stream>>>(x, wqkT_h, wqkT_l, qh, ql, kh, kl, vTh, vTl);
  k_flash<<<dim3(32, 120), 256, 0, stream>>>(qh, ql, kh, kl, vTh, vTl, rowstats, ob1, ob2);
  k_lam<<<120, 64, 0, stream>>>(rowstats, lw1, lb1, lw2, lb2, lam);
  k_ep<<<dim3(64, 120), 128, 0, stream>>>(ob1, ob2, lam, Wo, bo, h1);
  k_ck<<<29184, 256, 0, stream>>>(fw, cw2, cw4, cw8, cw16, cw32, ckh, ckl);
  k_conv<<<dim3(8, 4, 30), 256, 0, stream>>>(h1, ckh, ckl, fw, cb2, cb4, cb8, cb16, cb32, h2h, h2l);
  k_gattn<<<2048, 256, 0, stream>>>(h2h, h2l, gwT_h, gwT_l, maskw, gbq, gbk, gbv, gbo, (float*)d_out);
}